// Round 6
// baseline (107.832 us; speedup 1.0000x reference)
//
#include <hip/hip_runtime.h>
#include <math.h>

#define KC 32      // components
#define DD 256     // dims
#define QQ 16      // rank
#define NPTS 4096
#define LOG2PI_F 1.8378770664093453f

typedef unsigned short ushort_t;

// ws layout (float offsets). Two completion counters on separate 256B lines,
// both poison-initialized to 0xAAAAAAAA by the harness before every launch.
// cnt_early: released after {hb, vw, u}; cnt_late: after {minv, logc}.
#define CNT_EARLY  0
#define CNT_LATE   64
#define OFF_VW     128        // [K][D][2]  interleaved (psi_inv, psi_inv*mu)
#define OFF_MINV   16512      // [K][Q][Q]  M^-1 row-major
#define OFF_U      24704      // [K*Q]      u = Lhat . mu
#define OFF_LOGC   25216      // [K]        log_pi - 0.5*(D*log2pi + logdet C + ck)
#define OFF_HB     25248      // ushort region: [512][256] bf16 Lhat rows
#define POISON_U32 0xAAAAAAAAu

__device__ __forceinline__ ushort_t f2bf(float f) {
    union { float f; unsigned int u; } c; c.f = f;
    unsigned int u = c.u;
    return (ushort_t)((u + 0x7FFFu + ((u >> 16) & 1u)) >> 16);   // RNE
}

#define PSTR 260   // padded LDS row stride (2-way aliasing max)
struct PreS {
    float lamT[QQ * PSTR];    // [q][d]
    float lhatT[QQ * PSTR];   // [q][d]
    float mu[DD];
    float M[QQ * 17];         // 16x17
    float Y[QQ * 17];         // L^-1
    float part[8];
    float scal[2];            // sumLogPsi, ck
};

#define SXH 264   // bf16 X row stride (ushorts); 528 B row -> b128-aligned
#define STS 516   // t-matrix row stride (floats); 2064 B, 16B-aligned
#define SRS 36    // log-resp row stride
struct MainS {    // ~46 KB -> 3 blocks/CU
    ushort_t xh[16 * SXH];
    float    t[16 * STS];
    float    u[512];
    float    r[16 * SRS];
    float    lse[16];
};

using short8 = __attribute__((ext_vector_type(8))) short;   // 8 bf16 (4 VGPRs)
using f32x4  = __attribute__((ext_vector_type(4))) float;   // 4 fp32 acc

__global__ __launch_bounds__(256, 3) void fused_kernel(
    const float* __restrict__ X, const float* __restrict__ log_pi,
    const float* __restrict__ mu, const float* __restrict__ Lambda,
    const float* __restrict__ log_psi, float* __restrict__ ws,
    float* __restrict__ out)
{
    extern __shared__ char smem[];
    const int tid  = threadIdx.x;
    const int bid  = blockIdx.x;
    const int lane = tid & 63;
    const int wave = tid >> 6;
    unsigned int* cntE = reinterpret_cast<unsigned int*>(ws) + CNT_EARLY;
    unsigned int* cntL = reinterpret_cast<unsigned int*>(ws) + CNT_LATE;

    if (bid < KC) {
        // ================= PRECOMPUTE PATH (one component per block) =========
        PreS& s = *reinterpret_cast<PreS*>(smem);
        const int k = bid;
        ushort_t* hb = (ushort_t*)(ws + OFF_HB);
        const int d = tid;   // exactly D threads

        float Psi  = expf(log_psi[k * DD + d]) + 1.1e-5f;  // exp+1e-6 then +1e-5 jitter
        float vinv = 1.0f / Psi;
        float mud  = mu[k * DD + d];
        float wv   = vinv * mud;
        reinterpret_cast<float2*>(ws + OFF_VW + k * 2 * DD)[d] = make_float2(vinv, wv);
        s.mu[d] = mud;
        float logPsi = logf(Psi);
        float ckp = wv * mud;

        // load Lambda row d (16 floats), build Lhat
        float lam[QQ];
        const float4* lrow = reinterpret_cast<const float4*>(Lambda + (size_t)(k * DD + d) * QQ);
#pragma unroll
        for (int i = 0; i < 4; ++i) {
            float4 t = lrow[i];
            lam[4 * i + 0] = t.x; lam[4 * i + 1] = t.y;
            lam[4 * i + 2] = t.z; lam[4 * i + 3] = t.w;
        }
#pragma unroll
        for (int q = 0; q < QQ; ++q) {
            float lh = lam[q] * vinv;
            s.lamT[q * PSTR + d]  = lam[q];
            s.lhatT[q * PSTR + d] = lh;
            hb[(k * QQ + q) * DD + d] = f2bf(lh);
        }

        // block reduce sum(logPsi), sum(v*mu^2)
        float r0 = logPsi, r1 = ckp;
#pragma unroll
        for (int off = 32; off >= 1; off >>= 1) {
            r0 += __shfl_down(r0, off);
            r1 += __shfl_down(r1, off);
        }
        if ((tid & 63) == 0) { s.part[wave] = r0; s.part[4 + wave] = r1; }
        __syncthreads();                                            // S1
        if (tid == 0) {
            s.scal[0] = s.part[0] + s.part[1] + s.part[2] + s.part[3];
            s.scal[1] = s.part[4] + s.part[5] + s.part[6] + s.part[7];
        }

        // M = I + Lhat^T Lam : upper triangle (136 dots), threads 0..135
        if (tid < 136) {
            int q = 0, base = 0;
            while (tid >= base + (QQ - q)) { base += QQ - q; ++q; }
            int r = q + (tid - base);
            const float4* aq = reinterpret_cast<const float4*>(s.lhatT + q * PSTR);
            const float4* br = reinterpret_cast<const float4*>(s.lamT + r * PSTR);
            float acc = 0.f;
#pragma unroll
            for (int i = 0; i < DD / 4; ++i) {
                float4 a = aq[i], b = br[i];
                acc += a.x * b.x + a.y * b.y + a.z * b.z + a.w * b.w;
            }
            acc += (q == r) ? 1.0f : 0.0f;
            s.M[q * 17 + r] = acc;
            s.M[r * 17 + q] = acc;
        } else if (tid < 136 + QQ) {
            // u[q] = <Lhat[q], mu>
            int q = tid - 136;
            const float4* aq = reinterpret_cast<const float4*>(s.lhatT + q * PSTR);
            const float4* bm = reinterpret_cast<const float4*>(s.mu);
            float acc = 0.f;
#pragma unroll
            for (int i = 0; i < DD / 4; ++i) {
                float4 a = aq[i], b = bm[i];
                acc += a.x * b.x + a.y * b.y + a.z * b.z + a.w * b.w;
            }
            ws[OFF_U + k * QQ + q] = acc;
        }
        __syncthreads();                                            // S2
        // EARLY release: hb, vw, u are now complete (barrier drained all stores)
        if (tid == 0) {
            __threadfence();
            __hip_atomic_fetch_add(cntE, 1u, __ATOMIC_RELEASE, __HIP_MEMORY_SCOPE_AGENT);
        }

        // single-wave shuffle Cholesky + L^-1 (lanes 0..15 of wave 0)
        float logdetL = 0.f;
        if (wave == 0 && lane < QQ) {
            const int r = lane;
            float m[QQ], l[QQ];
#pragma unroll
            for (int c = 0; c < QQ; ++c) m[c] = s.M[r * 17 + c];
#pragma unroll
            for (int j = 0; j < QQ; ++j) {
                float djj = __shfl(m[j], j);
                float rinv = 1.0f / sqrtf(djj);
                l[j] = m[j] * rinv;                 // L[r][j], valid for r>=j
#pragma unroll
                for (int c = 0; c < QQ; ++c) {
                    if (c > j) m[c] -= l[j] * __shfl(l[j], c);
                }
            }
            // forward solve: column r of Y = L^-1
            float y[QQ];
#pragma unroll
            for (int j = 0; j < QQ; ++j) {
                float acc = (j == r) ? 1.0f : 0.0f;
#pragma unroll
                for (int i = 0; i < QQ; ++i) {
                    if (i < j) acc -= __shfl(l[i], j) * y[i];
                }
                y[j] = acc / __shfl(l[j], j);
            }
#pragma unroll
            for (int j = 0; j < QQ; ++j) s.Y[j * 17 + r] = y[j];
            // logdet(L): lane r holds L[r][r] in l[r]
            float dl = logf(l[r]);
            dl += __shfl_xor(dl, 1); dl += __shfl_xor(dl, 2);
            dl += __shfl_xor(dl, 4); dl += __shfl_xor(dl, 8);
            logdetL = dl;
        }
        __syncthreads();                                            // S3

        // Minv = Y^T Y (256 threads, one entry each)
        {
            int q = tid >> 4, r = tid & 15;
            float acc = 0.f;
#pragma unroll
            for (int j = 0; j < QQ; ++j) acc += s.Y[j * 17 + q] * s.Y[j * 17 + r];
            ws[OFF_MINV + k * QQ * QQ + tid] = acc;
        }
        if (tid == 0) {
            float logdet = s.scal[0] + 2.0f * logdetL;  // logdetC = sum log Psi + logdet M
            ws[OFF_LOGC + k] = log_pi[k] - 0.5f * ((float)DD * LOG2PI_F + logdet)
                             - 0.5f * s.scal[1];        // fold ck in
        }
        __syncthreads();                                            // S4
        // LATE release: minv + logc complete
        if (tid == 0) {
            __threadfence();
            __hip_atomic_fetch_add(cntL, 1u, __ATOMIC_RELEASE, __HIP_MEMORY_SCOPE_AGENT);
        }
        return;
    }

    // ================= MAIN PATH (16 rows x all 32 components) ===============
    MainS& s = *reinterpret_cast<MainS*>(smem);
    const int n0 = (bid - KC) * 16;
    const ushort_t* hB = (const ushort_t*)(ws + OFF_HB);
    const unsigned int target = POISON_U32 + (unsigned int)KC;

    // stage X tile (16x256) as bf16 (independent of ws)
    {
        const float4* gx = reinterpret_cast<const float4*>(X + (size_t)n0 * DD);
#pragma unroll
        for (int i = 0; i < 4; ++i) {
            int f = tid + i * 256;          // float4 index, 1024 total
            int row = f >> 6, d4 = f & 63;
            float4 v = gx[f];
            ushort4 h = make_ushort4(f2bf(v.x), f2bf(v.y), f2bf(v.z), f2bf(v.w));
            *reinterpret_cast<ushort4*>(s.xh + row * SXH + d4 * 4) = h;
        }
    }
    // EARLY wait: need {hb, u} for the MFMA stage. One lane, relaxed polls
    // (no invalidate), long sleep (low LLC line pressure), one acquire fence.
    if (tid == 0) {
        while (__hip_atomic_load(cntE, __ATOMIC_RELAXED, __HIP_MEMORY_SCOPE_AGENT) != target)
            __builtin_amdgcn_s_sleep(32);
        __builtin_amdgcn_fence(__ATOMIC_ACQUIRE, "agent");
    }
    __syncthreads();
    {
        s.u[tid]       = ws[OFF_U + tid];
        s.u[tid + 256] = ws[OFF_U + 256 + tid];
    }
    __syncthreads();

    // MFMA: t' = X . Lhat^T  (16 rows x 512 cols, K=256); wave w -> cols [w*128, w*128+128)
    {
        const int arow = lane & 15;          // A row m / C col within tile
        const int quad = lane >> 4;          // k-quad
        f32x4 acc[8];
#pragma unroll
        for (int t = 0; t < 8; ++t) acc[t] = (f32x4){0.f, 0.f, 0.f, 0.f};

        const ushort_t* sA = s.xh + arow * SXH + quad * 8;
        const ushort_t* gB = hB + (size_t)(wave * 128 + arow) * DD + quad * 8;
#pragma unroll
        for (int ks = 0; ks < 8; ++ks) {
            short8 a = *reinterpret_cast<const short8*>(sA + ks * 32);
#pragma unroll
            for (int t = 0; t < 8; ++t) {
                short8 b = *reinterpret_cast<const short8*>(gB + t * 16 * DD + ks * 32);
                acc[t] = __builtin_amdgcn_mfma_f32_16x16x32_bf16(a, b, acc[t], 0, 0, 0);
            }
        }
        // C/D layout: col = lane&15 (within tile), row = quad*4 + reg
#pragma unroll
        for (int t = 0; t < 8; ++t) {
            int cc = wave * 128 + t * 16 + arow;
#pragma unroll
            for (int r = 0; r < 4; ++r) {
                int rr = quad * 4 + r;
                s.t[rr * STS + cc] = acc[t][r] - s.u[cc];   // t = Lhat^T x - u
            }
        }
    }
    // LATE wait: need {minv, logc} for the corr epilogue (usually already done —
    // the Cholesky tail overlapped with our MFMA).
    if (tid == 0) {
        while (__hip_atomic_load(cntL, __ATOMIC_RELAXED, __HIP_MEMORY_SCOPE_AGENT) != target)
            __builtin_amdgcn_s_sleep(32);
        __builtin_amdgcn_fence(__ATOMIC_ACQUIRE, "agent");
    }
    __syncthreads();

    // epilogue: thread -> row=tid&15, comps {c0, c0+16}; X re-read from global (L1/L2-hot)
    {
        const int row = tid & 15, c0 = tid >> 4;
        const float4* xg = reinterpret_cast<const float4*>(X + (size_t)(n0 + row) * DD);
#pragma unroll
        for (int ci = 0; ci < 2; ++ci) {
            const int c = c0 + ci * 16;
            const float4* vw = reinterpret_cast<const float4*>(ws + OFF_VW + c * 2 * DD);
            float qx = 0.f, sx = 0.f;
#pragma unroll 8
            for (int i = 0; i < 64; ++i) {
                float4 x = xg[i];
                float4 a = vw[2 * i];        // v0 w0 v1 w1
                float4 b = vw[2 * i + 1];    // v2 w2 v3 w3
                qx += a.x * x.x * x.x + a.z * x.y * x.y + b.x * x.z * x.z + b.z * x.w * x.w;
                sx += a.y * x.x + a.w * x.y + b.y * x.z + b.w * x.w;
            }
            float t[QQ];
            const float* trow = s.t + row * STS + c * 16;   // 64B-aligned
#pragma unroll
            for (int i = 0; i < 4; ++i) {
                float4 tv = *reinterpret_cast<const float4*>(trow + i * 4);
                t[4 * i] = tv.x; t[4 * i + 1] = tv.y; t[4 * i + 2] = tv.z; t[4 * i + 3] = tv.w;
            }
            const float4* mi = reinterpret_cast<const float4*>(ws + OFF_MINV + c * 256);
            float corr = 0.f;
#pragma unroll
            for (int q = 0; q < QQ; ++q) {
                float4 m0 = mi[q * 4], m1 = mi[q * 4 + 1], m2 = mi[q * 4 + 2], m3 = mi[q * 4 + 3];
                float inner = m0.x * t[0] + m0.y * t[1] + m0.z * t[2] + m0.w * t[3]
                            + m1.x * t[4] + m1.y * t[5] + m1.z * t[6] + m1.w * t[7]
                            + m2.x * t[8] + m2.y * t[9] + m2.z * t[10] + m2.w * t[11]
                            + m3.x * t[12] + m3.y * t[13] + m3.z * t[14] + m3.w * t[15];
                corr += t[q] * inner;
            }
            float logc2 = ws[OFF_LOGC + c];
            s.r[row * SRS + c] = logc2 - 0.5f * (qx - 2.0f * sx - corr);
        }
    }
    __syncthreads();

    // logsumexp per row + outputs
    if (tid < 16) {
        float m = -INFINITY;
#pragma unroll
        for (int c = 0; c < KC; ++c) m = fmaxf(m, s.r[tid * SRS + c]);
        float sum = 0.f;
#pragma unroll
        for (int c = 0; c < KC; ++c) sum += expf(s.r[tid * SRS + c] - m);
        float lse = m + logf(sum);
        s.lse[tid] = lse;
        out[(size_t)NPTS * KC + n0 + tid] = lse;
    }
    __syncthreads();
    if (tid < 128) {
        int r = tid >> 3, i = tid & 7;
        float lse = s.lse[r];
        float4 v = *reinterpret_cast<const float4*>(s.r + r * SRS + i * 4);
        float4 o = make_float4(v.x - lse, v.y - lse, v.z - lse, v.w - lse);
        *reinterpret_cast<float4*>(out + (size_t)(n0 + r) * KC + i * 4) = o;
    }
}

extern "C" void kernel_launch(void* const* d_in, const int* in_sizes, int n_in,
                              void* d_out, int out_size, void* d_ws, size_t ws_size,
                              hipStream_t stream)
{
    (void)in_sizes; (void)n_in; (void)out_size; (void)ws_size;
    const float* X       = (const float*)d_in[0];
    const float* log_pi  = (const float*)d_in[1];
    const float* mu      = (const float*)d_in[2];
    const float* Lambda  = (const float*)d_in[3];
    const float* log_psi = (const float*)d_in[4];
    float* out = (float*)d_out;
    float* ws  = (float*)d_ws;   // ~363 KB used

    fused_kernel<<<dim3(KC + NPTS / 16), dim3(256), sizeof(MainS), stream>>>(
        X, log_pi, mu, Lambda, log_psi, ws, out);
}

// Round 7
// 96.628 us; speedup vs baseline: 1.1160x; 1.1160x over previous
//
#include <hip/hip_runtime.h>
#include <math.h>

#define KC 32      // components
#define DD 256     // dims
#define QQ 16      // rank
#define NPTS 4096
#define LOG2PI_F 1.8378770664093453f

typedef unsigned short ushort_t;

// ws layout (float offsets)
#define OFF_VW     0          // [K][D][2]  interleaved (psi_inv, psi_inv*mu)
#define OFF_MINV   16384      // [K][Q][Q]  M^-1 row-major
#define OFF_U      24576      // [K*Q]      u = Lhat . mu
#define OFF_LOGC   25088      // [K]        log_pi - 0.5*(D*log2pi + logdet C + ck)
#define OFF_HB     25120      // ushort region: [512][256] bf16 Lhat rows

__device__ __forceinline__ ushort_t f2bf(float f) {
    union { float f; unsigned int u; } c; c.f = f;
    unsigned int u = c.u;
    return (ushort_t)((u + 0x7FFFu + ((u >> 16) & 1u)) >> 16);   // RNE
}

// ---------------- Kernel 1: per-component precompute (32 blocks x 256 thr) ----
#define PSTR 260   // padded LDS row stride (2-way aliasing max)
__global__ __launch_bounds__(256) void precompute_kernel(
    const float* __restrict__ log_pi, const float* __restrict__ mu,
    const float* __restrict__ Lambda, const float* __restrict__ log_psi,
    float* __restrict__ ws)
{
    __shared__ __align__(16) float sLamT[QQ * PSTR];   // [q][d]
    __shared__ __align__(16) float sLhatT[QQ * PSTR];  // [q][d]
    __shared__ __align__(16) float sMu[DD];
    __shared__ float sM[QQ * 17];
    __shared__ float sL[QQ * 17];   // Cholesky factor L (lower)
    __shared__ float sY[QQ * 17];   // L^-1
    __shared__ float sCol[QQ];      // broadcast column during factorization
    __shared__ float sPart[8];
    __shared__ float sScal[2];

    const int k = blockIdx.x;
    const int tid = threadIdx.x;
    const int lane = tid & 63;
    const int wave = tid >> 6;
    ushort_t* hb = (ushort_t*)(ws + OFF_HB);
    const int d = tid;   // exactly D threads

    float Psi  = expf(log_psi[k * DD + d]) + 1.1e-5f;  // exp+1e-6 then +1e-5 jitter
    float vinv = 1.0f / Psi;
    float mud  = mu[k * DD + d];
    float wv   = vinv * mud;
    reinterpret_cast<float2*>(ws + OFF_VW + k * 2 * DD)[d] = make_float2(vinv, wv);
    sMu[d] = mud;
    float logPsi = logf(Psi);
    float ckp = wv * mud;

    // load Lambda row d (16 floats), build Lhat
    float lam[QQ];
    const float4* lrow = reinterpret_cast<const float4*>(Lambda + (size_t)(k * DD + d) * QQ);
#pragma unroll
    for (int i = 0; i < 4; ++i) {
        float4 t = lrow[i];
        lam[4 * i + 0] = t.x; lam[4 * i + 1] = t.y;
        lam[4 * i + 2] = t.z; lam[4 * i + 3] = t.w;
    }
#pragma unroll
    for (int q = 0; q < QQ; ++q) {
        float lh = lam[q] * vinv;
        sLamT[q * PSTR + d]  = lam[q];
        sLhatT[q * PSTR + d] = lh;
        hb[(k * QQ + q) * DD + d] = f2bf(lh);
    }

    // block reduce sum(logPsi), sum(v*mu^2)
    float r0 = logPsi, r1 = ckp;
#pragma unroll
    for (int off = 32; off >= 1; off >>= 1) {
        r0 += __shfl_down(r0, off);
        r1 += __shfl_down(r1, off);
    }
    if ((tid & 63) == 0) { sPart[wave] = r0; sPart[4 + wave] = r1; }
    __syncthreads();
    if (tid == 0) {
        sScal[0] = sPart[0] + sPart[1] + sPart[2] + sPart[3];
        sScal[1] = sPart[4] + sPart[5] + sPart[6] + sPart[7];
    }

    // M = I + Lhat^T Lam : all 256 threads, one (q,r) each
    {
        int q = tid >> 4, r = tid & 15;
        const float4* aq = reinterpret_cast<const float4*>(sLhatT + q * PSTR);
        const float4* br = reinterpret_cast<const float4*>(sLamT + r * PSTR);
        float acc = 0.f;
#pragma unroll
        for (int i = 0; i < DD / 4; ++i) {
            float4 a = aq[i], b = br[i];
            acc += a.x * b.x + a.y * b.y + a.z * b.z + a.w * b.w;
        }
        sM[q * 17 + r] = acc + ((q == r) ? 1.0f : 0.0f);
    }
    // u[q] = <Lhat[q], mu> (first 16 threads of wave 1 pattern avoided; use tid<16 after sync)
    __syncthreads();
    if (tid < QQ) {
        const float4* aq = reinterpret_cast<const float4*>(sLhatT + tid * PSTR);
        const float4* bm = reinterpret_cast<const float4*>(sMu);
        float acc = 0.f;
#pragma unroll
        for (int i = 0; i < DD / 4; ++i) {
            float4 a = aq[i], b = bm[i];
            acc += a.x * b.x + a.y * b.y + a.z * b.z + a.w * b.w;
        }
        ws[OFF_U + k * QQ + tid] = acc;
    }

    // Cholesky, lanes 0..15 of wave 0; per-column broadcast through LDS
    // (removes the ds_bpermute chain of the pure-shuffle version).
    float logdetL = 0.f;
    if (wave == 0 && lane < QQ) {
        const int r = lane;
        float m[QQ];   // row r of M (updated in place)
        float l[QQ];   // row r of L
#pragma unroll
        for (int c = 0; c < QQ; ++c) m[c] = sM[r * 17 + c];
#pragma unroll
        for (int j = 0; j < QQ; ++j) {
            float djj = __shfl(m[j], j);            // M[j][j] current
            float rinv = 1.0f / sqrtf(djj);
            l[j] = m[j] * rinv;                     // L[r][j] valid for r>=j
            sCol[r] = l[j];                         // publish column j
            // lanes read L[c][j] from LDS (broadcast-friendly)
#pragma unroll
            for (int c = 0; c < QQ; ++c)
                if (c > j) m[c] -= l[j] * sCol[c];
        }
#pragma unroll
        for (int j = 0; j < QQ; ++j) sL[r * 17 + j] = l[j];
        float dl = logf(l[r]);
        dl += __shfl_xor(dl, 1); dl += __shfl_xor(dl, 2);
        dl += __shfl_xor(dl, 4); dl += __shfl_xor(dl, 8);
        logdetL = dl;
        if (r == 0) sScal[0] = sScal[0];            // no-op keep
    }
    __syncthreads();

    // Y = L^-1, column per lane (lanes 0..15 of wave 0), rows via LDS L
    if (wave == 0 && lane < QQ) {
        const int c = lane;
        float y[QQ];
#pragma unroll
        for (int j = 0; j < QQ; ++j) {
            float acc = (j == c) ? 1.0f : 0.0f;
#pragma unroll
            for (int i = 0; i < QQ; ++i)
                if (i < j) acc -= sL[j * 17 + i] * y[i];
            y[j] = acc / sL[j * 17 + j];
        }
#pragma unroll
        for (int j = 0; j < QQ; ++j) sY[j * 17 + c] = y[j];
        if (c == 0) sPart[0] = logdetL;
    }
    __syncthreads();

    // Minv = Y^T Y (256 threads, one entry each)
    {
        int q = tid >> 4, r = tid & 15;
        float acc = 0.f;
#pragma unroll
        for (int j = 0; j < QQ; ++j) acc += sY[j * 17 + q] * sY[j * 17 + r];
        ws[OFF_MINV + k * QQ * QQ + tid] = acc;
    }
    if (tid == 0) {
        float logdet = sScal[0] + 2.0f * sPart[0];  // sum log Psi + logdet M
        ws[OFF_LOGC + k] = log_pi[k] - 0.5f * ((float)DD * LOG2PI_F + logdet)
                         - 0.5f * sScal[1];         // fold ck in
    }
}

// ---------------- Kernel 2: MFMA GEMM + epilogue + logsumexp ------------------
// grid 256 blocks, 256 threads. Block: 16 rows of X x ALL 32 components.
#define SXF 260   // fp32 X row stride (floats)
#define SXH 264   // bf16 X row stride (ushorts)
#define STS 516   // t-matrix row stride (floats)
#define SRS 36    // log-resp row stride

using short8 = __attribute__((ext_vector_type(8))) short;   // 8 bf16 (4 VGPRs)
using f32x4  = __attribute__((ext_vector_type(4))) float;   // 4 fp32 acc

__global__ __launch_bounds__(256, 2) void main_kernel(
    const float* __restrict__ X, const float* __restrict__ ws,
    float* __restrict__ out)
{
    const int tid  = threadIdx.x;
    const int lane = tid & 63;
    const int wave = tid >> 6;
    const int n0   = blockIdx.x * 16;
    const ushort_t* hB = (const ushort_t*)(ws + OFF_HB);

    __shared__ __align__(16) float    sXf[16 * SXF];
    __shared__ __align__(16) ushort_t sXh[16 * SXH];
    __shared__ __align__(16) float    sT[16 * STS];
    __shared__ float sU[512];
    __shared__ float sR[16 * SRS];
    __shared__ float sLse[16];

    // stage X tile (16x256): fp32 + bf16 copies
    {
        const float4* gx = reinterpret_cast<const float4*>(X + (size_t)n0 * DD);
#pragma unroll
        for (int i = 0; i < 4; ++i) {
            int f = tid + i * 256;          // float4 index, 1024 total
            int row = f >> 6, d4 = f & 63;
            float4 v = gx[f];
            *reinterpret_cast<float4*>(sXf + row * SXF + d4 * 4) = v;
            ushort4 h = make_ushort4(f2bf(v.x), f2bf(v.y), f2bf(v.z), f2bf(v.w));
            *reinterpret_cast<ushort4*>(sXh + row * SXH + d4 * 4) = h;
        }
        sU[tid]       = ws[OFF_U + tid];
        sU[tid + 256] = ws[OFF_U + 256 + tid];
    }
    __syncthreads();

    // MFMA: t' = X . Lhat^T  (16 rows x 512 cols, K=256); wave w -> cols [w*128,+128)
    {
        const int arow = lane & 15;          // A row m / C col within tile
        const int quad = lane >> 4;          // k-quad
        f32x4 acc[8];
#pragma unroll
        for (int t = 0; t < 8; ++t) acc[t] = (f32x4){0.f, 0.f, 0.f, 0.f};

        const ushort_t* sA = sXh + arow * SXH + quad * 8;
        const ushort_t* gB = hB + (size_t)(wave * 128 + arow) * DD + quad * 8;
#pragma unroll
        for (int ks = 0; ks < 8; ++ks) {
            short8 a = *reinterpret_cast<const short8*>(sA + ks * 32);
#pragma unroll
            for (int t = 0; t < 8; ++t) {
                short8 b = *reinterpret_cast<const short8*>(gB + t * 16 * DD + ks * 32);
                acc[t] = __builtin_amdgcn_mfma_f32_16x16x32_bf16(a, b, acc[t], 0, 0, 0);
            }
        }
        // C/D layout: col = lane&15 (within tile), row = quad*4 + reg
#pragma unroll
        for (int t = 0; t < 8; ++t) {
            int cc = wave * 128 + t * 16 + arow;
#pragma unroll
            for (int r = 0; r < 4; ++r) {
                int rr = quad * 4 + r;
                sT[rr * STS + cc] = acc[t][r] - sU[cc];   // t = Lhat^T x - u
            }
        }
    }
    __syncthreads();

    // epilogue: thread -> row=tid&15, comps {c0, c0+16}
    {
        const int row = tid & 15, c0 = tid >> 4;
        const float4* xr = reinterpret_cast<const float4*>(sXf + row * SXF);
#pragma unroll
        for (int ci = 0; ci < 2; ++ci) {
            const int c = c0 + ci * 16;
            const float4* vw = reinterpret_cast<const float4*>(ws + OFF_VW + c * 2 * DD);
            float qx = 0.f, sx = 0.f;
#pragma unroll 8
            for (int i = 0; i < 64; ++i) {
                float4 x = xr[i];
                float4 a = vw[2 * i];        // v0 w0 v1 w1
                float4 b = vw[2 * i + 1];    // v2 w2 v3 w3
                qx += a.x * x.x * x.x + a.z * x.y * x.y + b.x * x.z * x.z + b.z * x.w * x.w;
                sx += a.y * x.x + a.w * x.y + b.y * x.z + b.w * x.w;
            }
            float t[QQ];
            const float* trow = sT + row * STS + c * 16;
#pragma unroll
            for (int i = 0; i < 4; ++i) {
                float4 tv = *reinterpret_cast<const float4*>(trow + i * 4);
                t[4 * i] = tv.x; t[4 * i + 1] = tv.y; t[4 * i + 2] = tv.z; t[4 * i + 3] = tv.w;
            }
            const float4* mi = reinterpret_cast<const float4*>(ws + OFF_MINV + c * 256);
            float corr = 0.f;
#pragma unroll
            for (int q = 0; q < QQ; ++q) {
                float4 m0 = mi[q * 4], m1 = mi[q * 4 + 1], m2 = mi[q * 4 + 2], m3 = mi[q * 4 + 3];
                float inner = m0.x * t[0] + m0.y * t[1] + m0.z * t[2] + m0.w * t[3]
                            + m1.x * t[4] + m1.y * t[5] + m1.z * t[6] + m1.w * t[7]
                            + m2.x * t[8] + m2.y * t[9] + m2.z * t[10] + m2.w * t[11]
                            + m3.x * t[12] + m3.y * t[13] + m3.z * t[14] + m3.w * t[15];
                corr += t[q] * inner;
            }
            float logc2 = ws[OFF_LOGC + c];
            sR[row * SRS + c] = logc2 - 0.5f * (qx - 2.0f * sx - corr);
        }
    }
    __syncthreads();

    // logsumexp per row + outputs
    if (tid < 16) {
        float m = -INFINITY;
#pragma unroll
        for (int c = 0; c < KC; ++c) m = fmaxf(m, sR[tid * SRS + c]);
        float sum = 0.f;
#pragma unroll
        for (int c = 0; c < KC; ++c) sum += expf(sR[tid * SRS + c] - m);
        float lse = m + logf(sum);
        sLse[tid] = lse;
        out[(size_t)NPTS * KC + n0 + tid] = lse;
    }
    __syncthreads();
    if (tid < 128) {
        int r = tid >> 3, i = tid & 7;
        float lse = sLse[r];
        float4 v = *reinterpret_cast<const float4*>(sR + r * SRS + i * 4);
        float4 o = make_float4(v.x - lse, v.y - lse, v.z - lse, v.w - lse);
        *reinterpret_cast<float4*>(out + (size_t)(n0 + r) * KC + i * 4) = o;
    }
}

extern "C" void kernel_launch(void* const* d_in, const int* in_sizes, int n_in,
                              void* d_out, int out_size, void* d_ws, size_t ws_size,
                              hipStream_t stream)
{
    (void)in_sizes; (void)n_in; (void)out_size; (void)ws_size;
    const float* X       = (const float*)d_in[0];
    const float* log_pi  = (const float*)d_in[1];
    const float* mu      = (const float*)d_in[2];
    const float* Lambda  = (const float*)d_in[3];
    const float* log_psi = (const float*)d_in[4];
    float* out = (float*)d_out;
    float* ws  = (float*)d_ws;   // ~363 KB used

    precompute_kernel<<<dim3(KC), dim3(256), 0, stream>>>(log_pi, mu, Lambda, log_psi, ws);
    main_kernel<<<dim3(NPTS / 16), dim3(256), 0, stream>>>(X, ws, out);
}

// Round 8
// 94.966 us; speedup vs baseline: 1.1355x; 1.0175x over previous
//
#include <hip/hip_runtime.h>
#include <math.h>

#define KC 32      // components
#define DD 256     // dims
#define QQ 16      // rank
#define NPTS 4096
#define NROW 8     // rows per main block
#define LOG2PI_F 1.8378770664093453f

typedef unsigned short ushort_t;

// ws layout (float offsets)
#define OFF_U    0      // [512] u = Lhat . mu
#define OFF_LOGC 512    // [32]  log_pi - 0.5*(D*log2pi + logdetC + ck)
#define OFF_HB   544    // ushort [608][256] bf16 panel:
                        //   rows   0-511: Lhat (comp k, q) at row k*16+q
                        //   rows 512-543: V  = psi_inv (comp c at 512+c)
                        //   rows 544-575: W  = psi_inv*mu
                        //   rows 576-607: Minv (comp c at 576+c, entry q*16+r)

__device__ __forceinline__ ushort_t f2bf(float f) {
    union { float f; unsigned int u; } c; c.f = f;
    unsigned int u = c.u;
    return (ushort_t)((u + 0x7FFFu + ((u >> 16) & 1u)) >> 16);   // RNE
}
__device__ __forceinline__ float bf2f(ushort_t h) {
    union { unsigned int u; float f; } c; c.u = ((unsigned int)h) << 16;
    return c.f;
}

using short8 = __attribute__((ext_vector_type(8))) short;   // 8 bf16 (4 VGPRs)
using f32x4  = __attribute__((ext_vector_type(4))) float;   // 4 fp32 acc

// ---------------- Kernel 1: per-component precompute (32 blocks x 256 thr) ----
#define PSTR 260   // padded LDS row stride (2-way aliasing max)
__global__ __launch_bounds__(256) void precompute_kernel(
    const float* __restrict__ log_pi, const float* __restrict__ mu,
    const float* __restrict__ Lambda, const float* __restrict__ log_psi,
    float* __restrict__ ws)
{
    __shared__ __align__(16) float sLamT[QQ * PSTR];   // [q][d]
    __shared__ __align__(16) float sLhatT[QQ * PSTR];  // [q][d]
    __shared__ __align__(16) float sMu[DD];
    __shared__ float sM[QQ * 17];
    __shared__ float sL[QQ * 17];   // Cholesky factor L (lower)
    __shared__ float sY[QQ * 17];   // L^-1
    __shared__ float sCol[QQ];
    __shared__ float sPart[8];
    __shared__ float sScal[2];

    const int k = blockIdx.x;
    const int tid = threadIdx.x;
    const int lane = tid & 63;
    const int wave = tid >> 6;
    ushort_t* hb = (ushort_t*)(ws + OFF_HB);
    const int d = tid;   // exactly D threads

    float Psi  = expf(log_psi[k * DD + d]) + 1.1e-5f;  // exp+1e-6 then +1e-5 jitter
    float vinv = 1.0f / Psi;
    float mud  = mu[k * DD + d];
    float wv   = vinv * mud;
    hb[(512 + k) * DD + d] = f2bf(vinv);   // V row (bf16)
    hb[(544 + k) * DD + d] = f2bf(wv);     // W row (bf16)
    sMu[d] = mud;
    float logPsi = logf(Psi);
    float ckp = wv * mud;

    // load Lambda row d (16 floats), build Lhat
    float lam[QQ];
    const float4* lrow = reinterpret_cast<const float4*>(Lambda + (size_t)(k * DD + d) * QQ);
#pragma unroll
    for (int i = 0; i < 4; ++i) {
        float4 t = lrow[i];
        lam[4 * i + 0] = t.x; lam[4 * i + 1] = t.y;
        lam[4 * i + 2] = t.z; lam[4 * i + 3] = t.w;
    }
#pragma unroll
    for (int q = 0; q < QQ; ++q) {
        float lh = lam[q] * vinv;
        sLamT[q * PSTR + d]  = lam[q];
        sLhatT[q * PSTR + d] = lh;
        hb[(k * QQ + q) * DD + d] = f2bf(lh);
    }

    // block reduce sum(logPsi), sum(v*mu^2)
    float r0 = logPsi, r1 = ckp;
#pragma unroll
    for (int off = 32; off >= 1; off >>= 1) {
        r0 += __shfl_down(r0, off);
        r1 += __shfl_down(r1, off);
    }
    if ((tid & 63) == 0) { sPart[wave] = r0; sPart[4 + wave] = r1; }
    __syncthreads();
    if (tid == 0) {
        sScal[0] = sPart[0] + sPart[1] + sPart[2] + sPart[3];
        sScal[1] = sPart[4] + sPart[5] + sPart[6] + sPart[7];
    }

    // M = I + Lhat^T Lam : all 256 threads, one (q,r) each
    {
        int q = tid >> 4, r = tid & 15;
        const float4* aq = reinterpret_cast<const float4*>(sLhatT + q * PSTR);
        const float4* br = reinterpret_cast<const float4*>(sLamT + r * PSTR);
        float acc = 0.f;
#pragma unroll
        for (int i = 0; i < DD / 4; ++i) {
            float4 a = aq[i], b = br[i];
            acc += a.x * b.x + a.y * b.y + a.z * b.z + a.w * b.w;
        }
        sM[q * 17 + r] = acc + ((q == r) ? 1.0f : 0.0f);
    }
    __syncthreads();
    if (tid < QQ) {
        const float4* aq = reinterpret_cast<const float4*>(sLhatT + tid * PSTR);
        const float4* bm = reinterpret_cast<const float4*>(sMu);
        float acc = 0.f;
#pragma unroll
        for (int i = 0; i < DD / 4; ++i) {
            float4 a = aq[i], b = bm[i];
            acc += a.x * b.x + a.y * b.y + a.z * b.z + a.w * b.w;
        }
        ws[OFF_U + k * QQ + tid] = acc;
    }

    // Cholesky, lanes 0..15 of wave 0; per-column broadcast through LDS
    if (wave == 0 && lane < QQ) {
        const int r = lane;
        float m[QQ], l[QQ];
#pragma unroll
        for (int c = 0; c < QQ; ++c) m[c] = sM[r * 17 + c];
#pragma unroll
        for (int j = 0; j < QQ; ++j) {
            float djj = __shfl(m[j], j);
            float rinv = 1.0f / sqrtf(djj);
            l[j] = m[j] * rinv;
            sCol[r] = l[j];
#pragma unroll
            for (int c = 0; c < QQ; ++c)
                if (c > j) m[c] -= l[j] * sCol[c];
        }
#pragma unroll
        for (int j = 0; j < QQ; ++j) sL[r * 17 + j] = l[j];
        float dl = logf(l[r]);
        dl += __shfl_xor(dl, 1); dl += __shfl_xor(dl, 2);
        dl += __shfl_xor(dl, 4); dl += __shfl_xor(dl, 8);
        if (r == 0) sPart[1] = dl;   // logdetL
    }
    __syncthreads();

    // Y = L^-1, column per lane
    if (wave == 0 && lane < QQ) {
        const int c = lane;
        float y[QQ];
#pragma unroll
        for (int j = 0; j < QQ; ++j) {
            float acc = (j == c) ? 1.0f : 0.0f;
#pragma unroll
            for (int i = 0; i < QQ; ++i)
                if (i < j) acc -= sL[j * 17 + i] * y[i];
            y[j] = acc / sL[j * 17 + j];
        }
#pragma unroll
        for (int j = 0; j < QQ; ++j) sY[j * 17 + c] = y[j];
    }
    __syncthreads();

    // Minv = Y^T Y (256 threads, one entry each) -> bf16 panel row 576+k
    {
        int q = tid >> 4, r = tid & 15;
        float acc = 0.f;
#pragma unroll
        for (int j = 0; j < QQ; ++j) acc += sY[j * 17 + q] * sY[j * 17 + r];
        hb[(576 + k) * DD + tid] = f2bf(acc);   // tid == q*16+r
    }
    if (tid == 0) {
        float logdet = sScal[0] + 2.0f * sPart[1];  // sum log Psi + logdet M
        ws[OFF_LOGC + k] = log_pi[k] - 0.5f * ((float)DD * LOG2PI_F + logdet)
                         - 0.5f * sScal[1];         // fold ck in
    }
}

// ---------------- Kernel 2: MFMA GEMM + epilogue + logsumexp ------------------
// grid 512 blocks x 512 threads. Block: 8 rows of X x all 32 comps (+V,W tiles).
// 2 blocks/CU, 8 waves/block -> 4 waves/SIMD of TLP.
#define SXH 264   // bf16 X row stride (ushorts)
#define TSTR 520  // bf16 t row stride (ushorts)
#define QSTR 68   // qx/sx row stride (floats)
#define SRS 36

__global__ __launch_bounds__(512, 2) void main_kernel(
    const float* __restrict__ X, const float* __restrict__ ws,
    float* __restrict__ out)
{
    const int tid  = threadIdx.x;
    const int lane = tid & 63;
    const int wave = tid >> 6;         // 0..7
    const int n0   = blockIdx.x * NROW;
    const ushort_t* hB = (const ushort_t*)(ws + OFF_HB);

    __shared__ __align__(16) ushort_t xh[16 * SXH];    // rows 8-15 zero
    __shared__ __align__(16) ushort_t sT[NROW * TSTR]; // bf16 t
    __shared__ __align__(16) float    sQS[NROW * QSTR];// qx (0-31), sx (32-63)
    __shared__ float sU[512];
    __shared__ float sLogc[KC];
    __shared__ float sR[NROW * SRS];
    __shared__ float sLse[NROW];

    // ---- staging: 8 rows x 256 d as bf16; zero rows 8-15; u, logc ----
    {
        const float4* gx = reinterpret_cast<const float4*>(X + (size_t)n0 * DD);
        int row = tid >> 6, d4 = tid & 63;           // 512 float4 total
        float4 v = gx[tid];
        *reinterpret_cast<ushort4*>(&xh[row * SXH + d4 * 4]) =
            make_ushort4(f2bf(v.x), f2bf(v.y), f2bf(v.z), f2bf(v.w));
        int zr = 8 + (tid >> 6), zc = (tid & 63) * 4;
        *reinterpret_cast<ushort4*>(&xh[zr * SXH + zc]) = make_ushort4(0, 0, 0, 0);
        sU[tid] = ws[OFF_U + tid];
        if (tid < KC) sLogc[tid] = ws[OFF_LOGC + tid];
    }
    __syncthreads();

    // ---- MFMA: per wave 4 Lhat tiles + (waves 0-3) one special tile ----
    {
        const int arow = lane & 15;
        const int quad = lane >> 4;
        short8 a[8];
        const ushort_t* ab = xh + arow * SXH + quad * 8;
#pragma unroll
        for (int ks = 0; ks < 8; ++ks) a[ks] = *reinterpret_cast<const short8*>(ab + ks * 32);

#pragma unroll
        for (int i = 0; i < 4; ++i) {
            const int tile = wave * 4 + i;
            const ushort_t* gB = hB + (size_t)(tile * 16 + arow) * DD + quad * 8;
            f32x4 acc = (f32x4){0.f, 0.f, 0.f, 0.f};
#pragma unroll
            for (int ks = 0; ks < 8; ++ks)
                acc = __builtin_amdgcn_mfma_f32_16x16x32_bf16(
                    a[ks], *reinterpret_cast<const short8*>(gB + ks * 32), acc, 0, 0, 0);
            float uu = sU[tile * 16 + arow];
#pragma unroll
            for (int r = 0; r < 4; ++r) {
                int rr = quad * 4 + r;
                if (rr < NROW) sT[rr * TSTR + tile * 16 + arow] = f2bf(acc[r] - uu);
            }
        }
        if (wave < 4) {
            short8 aa[8];
            if (wave < 2) {   // A = X^2 (bf16) for qx tiles
#pragma unroll
                for (int ks = 0; ks < 8; ++ks) {
                    short8 sq;
#pragma unroll
                    for (int e = 0; e < 8; ++e) {
                        float xf = bf2f((ushort_t)a[ks][e]);
                        sq[e] = (short)f2bf(xf * xf);
                    }
                    aa[ks] = sq;
                }
            } else {
#pragma unroll
                for (int ks = 0; ks < 8; ++ks) aa[ks] = a[ks];
            }
            const ushort_t* gB = hB + (size_t)(512 + wave * 16 + arow) * DD + quad * 8;
            f32x4 acc = (f32x4){0.f, 0.f, 0.f, 0.f};
#pragma unroll
            for (int ks = 0; ks < 8; ++ks)
                acc = __builtin_amdgcn_mfma_f32_16x16x32_bf16(
                    aa[ks], *reinterpret_cast<const short8*>(gB + ks * 32), acc, 0, 0, 0);
            const int col = (wave & 1) * 16 + arow + ((wave >> 1) & 1) * 32;
#pragma unroll
            for (int r = 0; r < 4; ++r) {
                int rr = quad * 4 + r;
                if (rr < NROW) sQS[rr * QSTR + col] = acc[r];
            }
        }
    }
    __syncthreads();

    // ---- epilogue: thread = (half, row, c); corr via bf16 Minv panel ----
    {
        const int half = tid & 1;
        const int row  = (tid >> 1) & 7;
        const int c    = (tid >> 4) & 31;
        float t[16];
        {
            const ushort_t* tp = sT + row * TSTR + c * 16;
            short8 t0 = *reinterpret_cast<const short8*>(tp);
            short8 t1 = *reinterpret_cast<const short8*>(tp + 8);
#pragma unroll
            for (int e = 0; e < 8; ++e) {
                t[e]     = bf2f((ushort_t)t0[e]);
                t[8 + e] = bf2f((ushort_t)t1[e]);
            }
        }
        const ushort_t* mp = hB + (size_t)(576 + c) * DD + half * 128;
        float corr = 0.f;
#pragma unroll
        for (int q = 0; q < 8; ++q) {
            short8 m0 = *reinterpret_cast<const short8*>(mp + q * 16);
            short8 m1 = *reinterpret_cast<const short8*>(mp + q * 16 + 8);
            float inner = 0.f;
#pragma unroll
            for (int e = 0; e < 8; ++e)
                inner += bf2f((ushort_t)m0[e]) * t[e] + bf2f((ushort_t)m1[e]) * t[8 + e];
            corr += t[half * 8 + q] * inner;
        }
        corr += __shfl_xor(corr, 1);
        if (half == 0) {
            float qx = sQS[row * QSTR + c];
            float sx = sQS[row * QSTR + 32 + c];
            sR[row * SRS + c] = sLogc[c] - 0.5f * (qx - 2.0f * sx - corr);
        }
    }
    __syncthreads();

    // ---- logsumexp per row + outputs ----
    if (tid < NROW) {
        float m = -INFINITY;
#pragma unroll
        for (int c = 0; c < KC; ++c) m = fmaxf(m, sR[tid * SRS + c]);
        float sum = 0.f;
#pragma unroll
        for (int c = 0; c < KC; ++c) sum += expf(sR[tid * SRS + c] - m);
        float lse = m + logf(sum);
        sLse[tid] = lse;
        out[(size_t)NPTS * KC + n0 + tid] = lse;
    }
    __syncthreads();
    if (tid < NROW * 8) {
        int r = tid >> 3, i = tid & 7;
        float lse = sLse[r];
        float4 v = *reinterpret_cast<const float4*>(sR + r * SRS + i * 4);
        float4 o = make_float4(v.x - lse, v.y - lse, v.z - lse, v.w - lse);
        *reinterpret_cast<float4*>(out + (size_t)(n0 + r) * KC + i * 4) = o;
    }
}

extern "C" void kernel_launch(void* const* d_in, const int* in_sizes, int n_in,
                              void* d_out, int out_size, void* d_ws, size_t ws_size,
                              hipStream_t stream)
{
    (void)in_sizes; (void)n_in; (void)out_size; (void)ws_size;
    const float* X       = (const float*)d_in[0];
    const float* log_pi  = (const float*)d_in[1];
    const float* mu      = (const float*)d_in[2];
    const float* Lambda  = (const float*)d_in[3];
    const float* log_psi = (const float*)d_in[4];
    float* out = (float*)d_out;
    float* ws  = (float*)d_ws;   // ~313 KB used

    precompute_kernel<<<dim3(KC), dim3(256), 0, stream>>>(log_pi, mu, Lambda, log_psi, ws);
    main_kernel<<<dim3(NPTS / NROW), dim3(512), 0, stream>>>(X, ws, out);
}

// Round 9
// 84.901 us; speedup vs baseline: 1.2701x; 1.1186x over previous
//
#include <hip/hip_runtime.h>
#include <math.h>

#define KC 32      // components
#define DD 256     // dims
#define QQ 16      // rank
#define NPTS 4096
#define NROW 16    // rows per main block
#define LOG2PI_F 1.8378770664093453f

typedef unsigned short ushort_t;

// ws layout (float offsets)
#define OFF_U    0      // [512] u = Lhat . mu
#define OFF_LOGC 512    // [32]  log_pi - 0.5*(D*log2pi + logdetC + ck)
#define OFF_HB   544    // ushort [608][256] bf16 panel:
                        //   rows   0-511: Lhat (comp k, rank q) at row k*16+q
                        //   rows 512-543: V  = psi_inv (comp c at 512+c)
                        //   rows 544-575: W  = psi_inv*mu
                        //   rows 576-607: Minv (comp c at 576+c, entry q*16+r)

__device__ __forceinline__ ushort_t f2bf(float f) {
    union { float f; unsigned int u; } c; c.f = f;
    unsigned int u = c.u;
    return (ushort_t)((u + 0x7FFFu + ((u >> 16) & 1u)) >> 16);   // RNE
}
__device__ __forceinline__ float bf2f(ushort_t h) {
    union { unsigned int u; float f; } c; c.u = ((unsigned int)h) << 16;
    return c.f;
}

using short8 = __attribute__((ext_vector_type(8))) short;   // 8 bf16 (4 VGPRs)
using f32x4  = __attribute__((ext_vector_type(4))) float;   // 4 fp32 acc

// ---------------- Kernel 1: per-component precompute (32 blocks x 256 thr) ----
// M and u computed by wave-0 MFMA instead of 256-length LDS dot products.
#define HSTR 264   // bf16 LDS row stride (ushorts)
__global__ __launch_bounds__(256) void precompute_kernel(
    const float* __restrict__ log_pi, const float* __restrict__ mu,
    const float* __restrict__ Lambda, const float* __restrict__ log_psi,
    float* __restrict__ ws)
{
    __shared__ __align__(16) ushort_t lamH[QQ * HSTR];   // bf16 Lam  [q][d]
    __shared__ __align__(16) ushort_t lhatH[QQ * HSTR];  // bf16 Lhat [q][d]
    __shared__ __align__(16) ushort_t smuH[QQ * HSTR];   // row0 = bf16 mu, rows1-15 zero
    __shared__ float sM[QQ * 17];
    __shared__ float sL[QQ * 17];
    __shared__ float sY[QQ * 17];
    __shared__ float sCol[QQ];
    __shared__ float sPart[8];
    __shared__ float sScal[2];

    const int k = blockIdx.x;
    const int tid = threadIdx.x;
    const int lane = tid & 63;
    const int wave = tid >> 6;
    ushort_t* hb = (ushort_t*)(ws + OFF_HB);
    const int d = tid;   // exactly D threads

    float Psi  = expf(log_psi[k * DD + d]) + 1.1e-5f;  // exp+1e-6 then +1e-5 jitter
    float vinv = 1.0f / Psi;
    float mud  = mu[k * DD + d];
    float wv   = vinv * mud;
    hb[(512 + k) * DD + d] = f2bf(vinv);   // V row
    hb[(544 + k) * DD + d] = f2bf(wv);     // W row
    smuH[d] = f2bf(mud);                   // mu row 0
    float logPsi = logf(Psi);
    float ckp = wv * mud;

    // load Lambda row d (16 floats), build Lhat; bf16 to LDS + global panel
    {
        const float4* lrow = reinterpret_cast<const float4*>(Lambda + (size_t)(k * DD + d) * QQ);
#pragma unroll
        for (int i = 0; i < 4; ++i) {
            float4 t = lrow[i];
            float l0 = t.x, l1 = t.y, l2 = t.z, l3 = t.w;
            int q = 4 * i;
            lamH[(q + 0) * HSTR + d] = f2bf(l0);
            lamH[(q + 1) * HSTR + d] = f2bf(l1);
            lamH[(q + 2) * HSTR + d] = f2bf(l2);
            lamH[(q + 3) * HSTR + d] = f2bf(l3);
            ushort_t h0 = f2bf(l0 * vinv), h1 = f2bf(l1 * vinv);
            ushort_t h2 = f2bf(l2 * vinv), h3 = f2bf(l3 * vinv);
            lhatH[(q + 0) * HSTR + d] = h0;
            lhatH[(q + 1) * HSTR + d] = h1;
            lhatH[(q + 2) * HSTR + d] = h2;
            lhatH[(q + 3) * HSTR + d] = h3;
            hb[(k * QQ + q + 0) * DD + d] = h0;
            hb[(k * QQ + q + 1) * DD + d] = h1;
            hb[(k * QQ + q + 2) * DD + d] = h2;
            hb[(k * QQ + q + 3) * DD + d] = h3;
        }
    }
    // zero smuH rows 1-15 (990 ushort4)
#pragma unroll
    for (int i = 0; i < 4; ++i) {
        int idx = tid + i * 256;
        if (idx < 990)
            *reinterpret_cast<ushort4*>(smuH + HSTR + idx * 4) = make_ushort4(0, 0, 0, 0);
    }

    // block reduce sum(logPsi), sum(v*mu^2)
    float r0 = logPsi, r1 = ckp;
#pragma unroll
    for (int off = 32; off >= 1; off >>= 1) {
        r0 += __shfl_down(r0, off);
        r1 += __shfl_down(r1, off);
    }
    if ((tid & 63) == 0) { sPart[wave] = r0; sPart[4 + wave] = r1; }
    __syncthreads();                                            // S1
    if (tid == 0) {
        sScal[0] = sPart[0] + sPart[1] + sPart[2] + sPart[3];
        sScal[1] = sPart[4] + sPart[5] + sPart[6] + sPart[7];
    }

    // wave 0: M = Lhat . Lam^T and u = Lhat . mu via MFMA
    if (wave == 0) {
        const int arow = lane & 15;
        const int quad = lane >> 4;
        const ushort_t* pa = lhatH + arow * HSTR + quad * 8;
        const ushort_t* pl = lamH  + arow * HSTR + quad * 8;
        const ushort_t* pm = smuH  + arow * HSTR + quad * 8;
        f32x4 accM = (f32x4){0.f, 0.f, 0.f, 0.f};
        f32x4 accU = (f32x4){0.f, 0.f, 0.f, 0.f};
#pragma unroll
        for (int ks = 0; ks < 8; ++ks) {
            short8 a = *reinterpret_cast<const short8*>(pa + ks * 32);
            accM = __builtin_amdgcn_mfma_f32_16x16x32_bf16(
                a, *reinterpret_cast<const short8*>(pl + ks * 32), accM, 0, 0, 0);
            accU = __builtin_amdgcn_mfma_f32_16x16x32_bf16(
                a, *reinterpret_cast<const short8*>(pm + ks * 32), accU, 0, 0, 0);
        }
        // C layout: col=lane&15 (-> r / mu-col), row=quad*4+reg (-> q)
#pragma unroll
        for (int reg = 0; reg < 4; ++reg) {
            int q = quad * 4 + reg;
            sM[q * 17 + arow] = accM[reg] + ((q == arow) ? 1.0f : 0.0f);
        }
        if (arow == 0) {
#pragma unroll
            for (int reg = 0; reg < 4; ++reg)
                ws[OFF_U + k * QQ + quad * 4 + reg] = accU[reg];
        }
    }
    __syncthreads();                                            // S2

    // Cholesky, lanes 0..15 of wave 0; per-column broadcast through LDS
    if (wave == 0 && lane < QQ) {
        const int r = lane;
        float m[QQ], l[QQ];
#pragma unroll
        for (int c = 0; c < QQ; ++c) m[c] = sM[r * 17 + c];
#pragma unroll
        for (int j = 0; j < QQ; ++j) {
            float djj = __shfl(m[j], j);
            float rinv = 1.0f / sqrtf(djj);
            l[j] = m[j] * rinv;
            sCol[r] = l[j];
#pragma unroll
            for (int c = 0; c < QQ; ++c)
                if (c > j) m[c] -= l[j] * sCol[c];
        }
#pragma unroll
        for (int j = 0; j < QQ; ++j) sL[r * 17 + j] = l[j];
        float dl = logf(l[r]);
        dl += __shfl_xor(dl, 1); dl += __shfl_xor(dl, 2);
        dl += __shfl_xor(dl, 4); dl += __shfl_xor(dl, 8);
        if (r == 0) sPart[1] = dl;   // logdetL
    }
    __syncthreads();                                            // S3

    // Y = L^-1, column per lane
    if (wave == 0 && lane < QQ) {
        const int c = lane;
        float y[QQ];
#pragma unroll
        for (int j = 0; j < QQ; ++j) {
            float acc = (j == c) ? 1.0f : 0.0f;
#pragma unroll
            for (int i = 0; i < QQ; ++i)
                if (i < j) acc -= sL[j * 17 + i] * y[i];
            y[j] = acc / sL[j * 17 + j];
        }
#pragma unroll
        for (int j = 0; j < QQ; ++j) sY[j * 17 + c] = y[j];
    }
    __syncthreads();                                            // S4

    // Minv = Y^T Y (256 threads, one entry each) -> bf16 panel row 576+k
    {
        int q = tid >> 4, r = tid & 15;
        float acc = 0.f;
#pragma unroll
        for (int j = 0; j < QQ; ++j) acc += sY[j * 17 + q] * sY[j * 17 + r];
        hb[(576 + k) * DD + tid] = f2bf(acc);   // tid == q*16+r
    }
    if (tid == 0) {
        float logdet = sScal[0] + 2.0f * sPart[1];  // sum log Psi + logdet M
        ws[OFF_LOGC + k] = log_pi[k] - 0.5f * ((float)DD * LOG2PI_F + logdet)
                         - 0.5f * sScal[1];         // fold ck in
    }
}

// ---------------- Kernel 2: MFMA GEMM + epilogue + logsumexp ------------------
// grid 256 blocks x 512 threads. Block: 16 rows of X x all 32 comps (+V,W tiles).
// All 4 acc rows of every 16x16 MFMA are useful (no wasted half like NROW=8).
#define SXH 264   // bf16 X row stride (ushorts)
#define TSTR 520  // bf16 t row stride (ushorts)
#define QSTR 68   // qx/sx row stride (floats)
#define SRS 36

__global__ __launch_bounds__(512, 2) void main_kernel(
    const float* __restrict__ X, const float* __restrict__ ws,
    float* __restrict__ out)
{
    const int tid  = threadIdx.x;
    const int lane = tid & 63;
    const int wave = tid >> 6;         // 0..7
    const int n0   = blockIdx.x * NROW;
    const ushort_t* hB = (const ushort_t*)(ws + OFF_HB);

    __shared__ __align__(16) ushort_t xh[NROW * SXH];
    __shared__ __align__(16) ushort_t sT[NROW * TSTR]; // bf16 t
    __shared__ __align__(16) float    sQS[NROW * QSTR];// qx (cols 0-31), sx (32-63)
    __shared__ float sU[512];
    __shared__ float sLogc[KC];
    __shared__ float sR[NROW * SRS];
    __shared__ float sLse[NROW];

    // ---- staging: 16 rows x 256 d as bf16 (1024 float4, 2 per thread) ----
    {
        const float4* gx = reinterpret_cast<const float4*>(X + (size_t)n0 * DD);
#pragma unroll
        for (int i = 0; i < 2; ++i) {
            int f = tid + i * 512;
            int row = f >> 6, d4 = f & 63;
            float4 v = gx[f];
            *reinterpret_cast<ushort4*>(&xh[row * SXH + d4 * 4]) =
                make_ushort4(f2bf(v.x), f2bf(v.y), f2bf(v.z), f2bf(v.w));
        }
        sU[tid] = ws[OFF_U + tid];
        if (tid < KC) sLogc[tid] = ws[OFF_LOGC + tid];
    }
    __syncthreads();

    // ---- MFMA: per wave 4 Lhat tiles + (waves 0-3) one special tile ----
    {
        const int arow = lane & 15;
        const int quad = lane >> 4;
        short8 a[8];
        const ushort_t* ab = xh + arow * SXH + quad * 8;
#pragma unroll
        for (int ks = 0; ks < 8; ++ks) a[ks] = *reinterpret_cast<const short8*>(ab + ks * 32);

#pragma unroll
        for (int i = 0; i < 4; ++i) {
            const int tile = wave * 4 + i;
            const ushort_t* gB = hB + (size_t)(tile * 16 + arow) * DD + quad * 8;
            f32x4 acc = (f32x4){0.f, 0.f, 0.f, 0.f};
#pragma unroll
            for (int ks = 0; ks < 8; ++ks)
                acc = __builtin_amdgcn_mfma_f32_16x16x32_bf16(
                    a[ks], *reinterpret_cast<const short8*>(gB + ks * 32), acc, 0, 0, 0);
            float uu = sU[tile * 16 + arow];
#pragma unroll
            for (int r = 0; r < 4; ++r)
                sT[(quad * 4 + r) * TSTR + tile * 16 + arow] = f2bf(acc[r] - uu);
        }
        if (wave < 4) {
            short8 aa[8];
            if (wave < 2) {   // A = X^2 (bf16) for qx tiles
#pragma unroll
                for (int ks = 0; ks < 8; ++ks) {
                    short8 sq;
#pragma unroll
                    for (int e = 0; e < 8; ++e) {
                        float xf = bf2f((ushort_t)a[ks][e]);
                        sq[e] = (short)f2bf(xf * xf);
                    }
                    aa[ks] = sq;
                }
            } else {
#pragma unroll
                for (int ks = 0; ks < 8; ++ks) aa[ks] = a[ks];
            }
            const ushort_t* gB = hB + (size_t)(512 + wave * 16 + arow) * DD + quad * 8;
            f32x4 acc = (f32x4){0.f, 0.f, 0.f, 0.f};
#pragma unroll
            for (int ks = 0; ks < 8; ++ks)
                acc = __builtin_amdgcn_mfma_f32_16x16x32_bf16(
                    aa[ks], *reinterpret_cast<const short8*>(gB + ks * 32), acc, 0, 0, 0);
            const int col = (wave & 1) * 16 + arow + ((wave >> 1) & 1) * 32;
#pragma unroll
            for (int r = 0; r < 4; ++r)
                sQS[(quad * 4 + r) * QSTR + col] = acc[r];
        }
    }
    __syncthreads();

    // ---- epilogue: thread = (half, row, c0); corr via bf16 Minv panel ----
    {
        const int half = tid & 1;
        const int row  = (tid >> 1) & 15;
        const int c0   = tid >> 5;          // 0..15
#pragma unroll
        for (int ci = 0; ci < 2; ++ci) {
            const int c = c0 + ci * 16;
            float t[16];
            {
                const ushort_t* tp = sT + row * TSTR + c * 16;
                short8 t0 = *reinterpret_cast<const short8*>(tp);
                short8 t1 = *reinterpret_cast<const short8*>(tp + 8);
#pragma unroll
                for (int e = 0; e < 8; ++e) {
                    t[e]     = bf2f((ushort_t)t0[e]);
                    t[8 + e] = bf2f((ushort_t)t1[e]);
                }
            }
            const ushort_t* mp = hB + (size_t)(576 + c) * DD + half * 128;
            float corr = 0.f;
#pragma unroll
            for (int q = 0; q < 8; ++q) {
                short8 m0 = *reinterpret_cast<const short8*>(mp + q * 16);
                short8 m1 = *reinterpret_cast<const short8*>(mp + q * 16 + 8);
                float inner = 0.f;
#pragma unroll
                for (int e = 0; e < 8; ++e)
                    inner += bf2f((ushort_t)m0[e]) * t[e] + bf2f((ushort_t)m1[e]) * t[8 + e];
                corr += t[half * 8 + q] * inner;
            }
            corr += __shfl_xor(corr, 1);
            if (half == 0) {
                float qx = sQS[row * QSTR + c];
                float sx = sQS[row * QSTR + 32 + c];
                sR[row * SRS + c] = sLogc[c] - 0.5f * (qx - 2.0f * sx - corr);
            }
        }
    }
    __syncthreads();

    // ---- logsumexp per row + outputs ----
    if (tid < NROW) {
        float m = -INFINITY;
#pragma unroll
        for (int c = 0; c < KC; ++c) m = fmaxf(m, sR[tid * SRS + c]);
        float sum = 0.f;
#pragma unroll
        for (int c = 0; c < KC; ++c) sum += expf(sR[tid * SRS + c] - m);
        float lse = m + logf(sum);
        sLse[tid] = lse;
        out[(size_t)NPTS * KC + n0 + tid] = lse;
    }
    __syncthreads();
    if (tid < NROW * 8) {
        int r = tid >> 3, i = tid & 7;
        float lse = sLse[r];
        float4 v = *reinterpret_cast<const float4*>(sR + r * SRS + i * 4);
        float4 o = make_float4(v.x - lse, v.y - lse, v.z - lse, v.w - lse);
        *reinterpret_cast<float4*>(out + (size_t)(n0 + r) * KC + i * 4) = o;
    }
}

extern "C" void kernel_launch(void* const* d_in, const int* in_sizes, int n_in,
                              void* d_out, int out_size, void* d_ws, size_t ws_size,
                              hipStream_t stream)
{
    (void)in_sizes; (void)n_in; (void)out_size; (void)ws_size;
    const float* X       = (const float*)d_in[0];
    const float* log_pi  = (const float*)d_in[1];
    const float* mu      = (const float*)d_in[2];
    const float* Lambda  = (const float*)d_in[3];
    const float* log_psi = (const float*)d_in[4];
    float* out = (float*)d_out;
    float* ws  = (float*)d_ws;   // ~306 KB used

    precompute_kernel<<<dim3(KC), dim3(256), 0, stream>>>(log_pi, mu, Lambda, log_psi, ws);
    main_kernel<<<dim3(NPTS / NROW), dim3(512), 0, stream>>>(X, ws, out);
}

// Round 10
// 84.268 us; speedup vs baseline: 1.2796x; 1.0075x over previous
//
#include <hip/hip_runtime.h>
#include <math.h>

#define KC 32      // components
#define DD 256     // dims
#define QQ 16      // rank
#define NPTS 4096
#define NROW 16    // rows per main block
#define LOG2PI_F 1.8378770664093453f

typedef unsigned short ushort_t;

// ws layout (float offsets)
#define OFF_U    0      // [512] u = Lhat . mu
#define OFF_LOGC 512    // [32]  log_pi - 0.5*(D*log2pi + logdetC + ck)
#define OFF_HB   544    // ushort [608][256] bf16 panel:
                        //   rows   0-511: Lhat (comp k, rank q) at row k*16+q
                        //   rows 512-543: V  = psi_inv (comp c at 512+c)
                        //   rows 544-575: W  = psi_inv*mu
                        //   rows 576-607: Minv (comp c at 576+c, entry q*16+r)

__device__ __forceinline__ ushort_t f2bf(float f) {
    union { float f; unsigned int u; } c; c.f = f;
    unsigned int u = c.u;
    return (ushort_t)((u + 0x7FFFu + ((u >> 16) & 1u)) >> 16);   // RNE
}
__device__ __forceinline__ float bf2f(ushort_t h) {
    union { unsigned int u; float f; } c; c.u = ((unsigned int)h) << 16;
    return c.f;
}

using short8 = __attribute__((ext_vector_type(8))) short;   // 8 bf16 (4 VGPRs)
using f32x4  = __attribute__((ext_vector_type(4))) float;   // 4 fp32 acc

// ---------------- Kernel 1: per-component precompute (32 blocks x 256 thr) ----
// M and u via wave-0 MFMA; only 2 block barriers (wave-0 sections need none).
#define HSTR 264   // bf16 LDS row stride (ushorts)
__global__ __launch_bounds__(256) void precompute_kernel(
    const float* __restrict__ log_pi, const float* __restrict__ mu,
    const float* __restrict__ Lambda, const float* __restrict__ log_psi,
    float* __restrict__ ws)
{
    __shared__ __align__(16) ushort_t lamH[QQ * HSTR];   // bf16 Lam  [q][d]
    __shared__ __align__(16) ushort_t lhatH[QQ * HSTR];  // bf16 Lhat [q][d]
    __shared__ __align__(16) ushort_t smuH[QQ * HSTR];   // row0 = bf16 mu, rows1-15 zero
    __shared__ float sM[QQ * 17];
    __shared__ float sL[QQ * 17];
    __shared__ float sY[QQ * 17];
    __shared__ float sPart[8];
    __shared__ float sScal[2];

    const int k = blockIdx.x;
    const int tid = threadIdx.x;
    const int lane = tid & 63;
    const int wave = tid >> 6;
    ushort_t* hb = (ushort_t*)(ws + OFF_HB);
    const int d = tid;   // exactly D threads

    float Psi  = expf(log_psi[k * DD + d]) + 1.1e-5f;  // exp+1e-6 then +1e-5 jitter
    float vinv = 1.0f / Psi;
    float mud  = mu[k * DD + d];
    float wv   = vinv * mud;
    hb[(512 + k) * DD + d] = f2bf(vinv);   // V row
    hb[(544 + k) * DD + d] = f2bf(wv);     // W row
    smuH[d] = f2bf(mud);                   // mu row 0
    float logPsi = logf(Psi);
    float ckp = wv * mud;

    // load Lambda row d (16 floats), build Lhat; bf16 to LDS + global panel
    {
        const float4* lrow = reinterpret_cast<const float4*>(Lambda + (size_t)(k * DD + d) * QQ);
#pragma unroll
        for (int i = 0; i < 4; ++i) {
            float4 t = lrow[i];
            float l0 = t.x, l1 = t.y, l2 = t.z, l3 = t.w;
            int q = 4 * i;
            lamH[(q + 0) * HSTR + d] = f2bf(l0);
            lamH[(q + 1) * HSTR + d] = f2bf(l1);
            lamH[(q + 2) * HSTR + d] = f2bf(l2);
            lamH[(q + 3) * HSTR + d] = f2bf(l3);
            ushort_t h0 = f2bf(l0 * vinv), h1 = f2bf(l1 * vinv);
            ushort_t h2 = f2bf(l2 * vinv), h3 = f2bf(l3 * vinv);
            lhatH[(q + 0) * HSTR + d] = h0;
            lhatH[(q + 1) * HSTR + d] = h1;
            lhatH[(q + 2) * HSTR + d] = h2;
            lhatH[(q + 3) * HSTR + d] = h3;
            hb[(k * QQ + q + 0) * DD + d] = h0;
            hb[(k * QQ + q + 1) * DD + d] = h1;
            hb[(k * QQ + q + 2) * DD + d] = h2;
            hb[(k * QQ + q + 3) * DD + d] = h3;
        }
    }
    // zero smuH rows 1-15 (990 ushort4)
#pragma unroll
    for (int i = 0; i < 4; ++i) {
        int idx = tid + i * 256;
        if (idx < 990)
            *reinterpret_cast<ushort4*>(smuH + HSTR + idx * 4) = make_ushort4(0, 0, 0, 0);
    }

    // block reduce sum(logPsi), sum(v*mu^2)
    float r0 = logPsi, r1 = ckp;
#pragma unroll
    for (int off = 32; off >= 1; off >>= 1) {
        r0 += __shfl_down(r0, off);
        r1 += __shfl_down(r1, off);
    }
    if ((tid & 63) == 0) { sPart[wave] = r0; sPart[4 + wave] = r1; }
    __syncthreads();                                            // B1 (also fences staging)
    if (tid == 0) {
        sScal[0] = sPart[0] + sPart[1] + sPart[2] + sPart[3];
        sScal[1] = sPart[4] + sPart[5] + sPart[6] + sPart[7];
    }

    // ---- wave 0 only: MFMA M,u -> Cholesky -> L^-1 (intra-wave LDS ordering) ----
    if (wave == 0) {
        const int arow = lane & 15;
        const int quad = lane >> 4;
        const ushort_t* pa = lhatH + arow * HSTR + quad * 8;
        const ushort_t* pl = lamH  + arow * HSTR + quad * 8;
        const ushort_t* pm = smuH  + arow * HSTR + quad * 8;
        f32x4 accM = (f32x4){0.f, 0.f, 0.f, 0.f};
        f32x4 accU = (f32x4){0.f, 0.f, 0.f, 0.f};
#pragma unroll
        for (int ks = 0; ks < 8; ++ks) {
            short8 a = *reinterpret_cast<const short8*>(pa + ks * 32);
            accM = __builtin_amdgcn_mfma_f32_16x16x32_bf16(
                a, *reinterpret_cast<const short8*>(pl + ks * 32), accM, 0, 0, 0);
            accU = __builtin_amdgcn_mfma_f32_16x16x32_bf16(
                a, *reinterpret_cast<const short8*>(pm + ks * 32), accU, 0, 0, 0);
        }
        // C layout: col=lane&15 (-> r), row=quad*4+reg (-> q)
#pragma unroll
        for (int reg = 0; reg < 4; ++reg) {
            int q = quad * 4 + reg;
            sM[q * 17 + arow] = accM[reg] + ((q == arow) ? 1.0f : 0.0f);
        }
        if (arow == 0) {
#pragma unroll
            for (int reg = 0; reg < 4; ++reg)
                ws[OFF_U + k * QQ + quad * 4 + reg] = accU[reg];
        }

        // Cholesky (lanes 0..15), column broadcast through LDS sL row 16 slot
        if (lane < QQ) {
            const int r = lane;
            float m[QQ], l[QQ];
#pragma unroll
            for (int c = 0; c < QQ; ++c) m[c] = sM[r * 17 + c];
#pragma unroll
            for (int j = 0; j < QQ; ++j) {
                float djj = __shfl(m[j], j);
                float rinv = 1.0f / sqrtf(djj);
                l[j] = m[j] * rinv;
                sL[r * 17 + 16] = l[j];          // publish column j (slot 16)
#pragma unroll
                for (int c = 0; c < QQ; ++c)
                    if (c > j) m[c] -= l[j] * sL[c * 17 + 16];
            }
#pragma unroll
            for (int j = 0; j < QQ; ++j) sL[r * 17 + j] = l[j];
            float dl = logf(l[r]);
            dl += __shfl_xor(dl, 1); dl += __shfl_xor(dl, 2);
            dl += __shfl_xor(dl, 4); dl += __shfl_xor(dl, 8);
            if (r == 0) sPart[1] = dl;   // logdetL

            // Y = L^-1, column per lane
            float y[QQ];
#pragma unroll
            for (int j = 0; j < QQ; ++j) {
                float acc = (j == r) ? 1.0f : 0.0f;
#pragma unroll
                for (int i = 0; i < QQ; ++i)
                    if (i < j) acc -= sL[j * 17 + i] * y[i];
                y[j] = acc / sL[j * 17 + j];
            }
#pragma unroll
            for (int j = 0; j < QQ; ++j) sY[j * 17 + r] = y[j];
        }
    }
    __syncthreads();                                            // B2

    // Minv = Y^T Y (256 threads, one entry each) -> bf16 panel row 576+k
    {
        int q = tid >> 4, r = tid & 15;
        float acc = 0.f;
#pragma unroll
        for (int j = 0; j < QQ; ++j) acc += sY[j * 17 + q] * sY[j * 17 + r];
        hb[(576 + k) * DD + tid] = f2bf(acc);   // tid == q*16+r
    }
    if (tid == 0) {
        float logdet = sScal[0] + 2.0f * sPart[1];  // sum log Psi + logdet M
        ws[OFF_LOGC + k] = log_pi[k] - 0.5f * ((float)DD * LOG2PI_F + logdet)
                         - 0.5f * sScal[1];         // fold ck in
    }
}

// ---------------- Kernel 2: MFMA GEMM + epilogue + logsumexp ------------------
// grid 256 blocks x 512 threads, 16 rows x all 32 comps.
// B-frags for all 4 Lhat tiles prefetched -> 4 independent MFMA chains (ks-major).
#define SXH 264   // bf16 X row stride (ushorts)
#define TSTR 520  // bf16 t row stride (ushorts)
#define QSTR 68   // qx/sx row stride (floats)
#define MSTR 264  // Minv LDS row stride (ushorts)
#define SRS 36

__global__ __launch_bounds__(512, 2) void main_kernel(
    const float* __restrict__ X, const float* __restrict__ ws,
    float* __restrict__ out)
{
    const int tid  = threadIdx.x;
    const int lane = tid & 63;
    const int wave = tid >> 6;         // 0..7
    const int n0   = blockIdx.x * NROW;
    const ushort_t* hB = (const ushort_t*)(ws + OFF_HB);

    __shared__ __align__(16) ushort_t xh[NROW * SXH];
    __shared__ __align__(16) ushort_t sT[NROW * TSTR];  // bf16 t
    __shared__ __align__(16) ushort_t sMin[KC * MSTR];  // bf16 Minv (staged)
    __shared__ __align__(16) float    sQS[NROW * QSTR]; // qx (0-31), sx (32-63)
    __shared__ float sU[512];
    __shared__ float sLogc[KC];
    __shared__ float sR[NROW * SRS];
    __shared__ float sLse[NROW];

    // ---- staging: X rows as bf16 + Minv panel + u + logc ----
    {
        const float4* gx = reinterpret_cast<const float4*>(X + (size_t)n0 * DD);
#pragma unroll
        for (int i = 0; i < 2; ++i) {
            int f = tid + i * 512;
            int row = f >> 6, d4 = f & 63;
            float4 v = gx[f];
            *reinterpret_cast<ushort4*>(&xh[row * SXH + d4 * 4]) =
                make_ushort4(f2bf(v.x), f2bf(v.y), f2bf(v.z), f2bf(v.w));
        }
        // Minv: 32 rows x 256 ushorts = 2048 ushort4, 4 per thread
#pragma unroll
        for (int i = 0; i < 4; ++i) {
            int f = tid + i * 512;
            int row = f >> 6, c4 = f & 63;
            *reinterpret_cast<ushort4*>(&sMin[row * MSTR + c4 * 4]) =
                *reinterpret_cast<const ushort4*>(hB + (size_t)(576 + row) * DD + c4 * 4);
        }
        sU[tid] = ws[OFF_U + tid];
        if (tid < KC) sLogc[tid] = ws[OFF_LOGC + tid];
    }
    __syncthreads();

    // ---- MFMA: prefetch all B, then ks-major = 4 independent chains ----
    {
        const int arow = lane & 15;
        const int quad = lane >> 4;
        short8 a[8];
        const ushort_t* ab = xh + arow * SXH + quad * 8;
#pragma unroll
        for (int ks = 0; ks < 8; ++ks) a[ks] = *reinterpret_cast<const short8*>(ab + ks * 32);

        short8 b[4][8];
#pragma unroll
        for (int i = 0; i < 4; ++i) {
            const ushort_t* gB = hB + (size_t)((wave * 4 + i) * 16 + arow) * DD + quad * 8;
#pragma unroll
            for (int ks = 0; ks < 8; ++ks)
                b[i][ks] = *reinterpret_cast<const short8*>(gB + ks * 32);
        }
        f32x4 acc[4];
#pragma unroll
        for (int i = 0; i < 4; ++i) acc[i] = (f32x4){0.f, 0.f, 0.f, 0.f};
#pragma unroll
        for (int ks = 0; ks < 8; ++ks)
#pragma unroll
            for (int i = 0; i < 4; ++i)
                acc[i] = __builtin_amdgcn_mfma_f32_16x16x32_bf16(a[ks], b[i][ks], acc[i], 0, 0, 0);
#pragma unroll
        for (int i = 0; i < 4; ++i) {
            const int tile = wave * 4 + i;
            float uu = sU[tile * 16 + arow];
#pragma unroll
            for (int r = 0; r < 4; ++r)
                sT[(quad * 4 + r) * TSTR + tile * 16 + arow] = f2bf(acc[i][r] - uu);
        }
        if (wave < 4) {
            short8 aa[8];
            if (wave < 2) {   // A = X^2 (bf16) for qx tiles
#pragma unroll
                for (int ks = 0; ks < 8; ++ks) {
                    short8 sq;
#pragma unroll
                    for (int e = 0; e < 8; ++e) {
                        float xf = bf2f((ushort_t)a[ks][e]);
                        sq[e] = (short)f2bf(xf * xf);
                    }
                    aa[ks] = sq;
                }
            } else {
#pragma unroll
                for (int ks = 0; ks < 8; ++ks) aa[ks] = a[ks];
            }
            const ushort_t* gB = hB + (size_t)(512 + wave * 16 + arow) * DD + quad * 8;
            f32x4 accs = (f32x4){0.f, 0.f, 0.f, 0.f};
#pragma unroll
            for (int ks = 0; ks < 8; ++ks)
                accs = __builtin_amdgcn_mfma_f32_16x16x32_bf16(
                    aa[ks], *reinterpret_cast<const short8*>(gB + ks * 32), accs, 0, 0, 0);
            const int col = (wave & 1) * 16 + arow + ((wave >> 1) & 1) * 32;
#pragma unroll
            for (int r = 0; r < 4; ++r)
                sQS[(quad * 4 + r) * QSTR + col] = accs[r];
        }
    }
    __syncthreads();

    // ---- epilogue: thread = (half, row, c0); corr via LDS Minv ----
    {
        const int half = tid & 1;
        const int row  = (tid >> 1) & 15;
        const int c0   = tid >> 5;          // 0..15
#pragma unroll
        for (int ci = 0; ci < 2; ++ci) {
            const int c = c0 + ci * 16;
            float t[16];
            {
                const ushort_t* tp = sT + row * TSTR + c * 16;
                short8 t0 = *reinterpret_cast<const short8*>(tp);
                short8 t1 = *reinterpret_cast<const short8*>(tp + 8);
#pragma unroll
                for (int e = 0; e < 8; ++e) {
                    t[e]     = bf2f((ushort_t)t0[e]);
                    t[8 + e] = bf2f((ushort_t)t1[e]);
                }
            }
            const ushort_t* mp = sMin + c * MSTR + half * 128;
            float corr = 0.f;
#pragma unroll
            for (int q = 0; q < 8; ++q) {
                short8 m0 = *reinterpret_cast<const short8*>(mp + q * 16);
                short8 m1 = *reinterpret_cast<const short8*>(mp + q * 16 + 8);
                float inner = 0.f;
#pragma unroll
                for (int e = 0; e < 8; ++e)
                    inner += bf2f((ushort_t)m0[e]) * t[e] + bf2f((ushort_t)m1[e]) * t[8 + e];
                corr += t[half * 8 + q] * inner;
            }
            corr += __shfl_xor(corr, 1);
            if (half == 0) {
                float qx = sQS[row * QSTR + c];
                float sx = sQS[row * QSTR + 32 + c];
                sR[row * SRS + c] = sLogc[c] - 0.5f * (qx - 2.0f * sx - corr);
            }
        }
    }
    __syncthreads();

    // ---- logsumexp per row + outputs ----
    if (tid < NROW) {
        float m = -INFINITY;
#pragma unroll
        for (int c = 0; c < KC; ++c) m = fmaxf(m, sR[tid * SRS + c]);
        float sum = 0.f;
#pragma unroll
        for (int c = 0; c < KC; ++c) sum += expf(sR[tid * SRS + c] - m);
        float lse = m + logf(sum);
        sLse[tid] = lse;
        out[(size_t)NPTS * KC + n0 + tid] = lse;
    }
    __syncthreads();
    if (tid < NROW * 8) {
        int r = tid >> 3, i = tid & 7;
        float lse = sLse[r];
        float4 v = *reinterpret_cast<const float4*>(sR + r * SRS + i * 4);
        float4 o = make_float4(v.x - lse, v.y - lse, v.z - lse, v.w - lse);
        *reinterpret_cast<float4*>(out + (size_t)(n0 + r) * KC + i * 4) = o;
    }
}

extern "C" void kernel_launch(void* const* d_in, const int* in_sizes, int n_in,
                              void* d_out, int out_size, void* d_ws, size_t ws_size,
                              hipStream_t stream)
{
    (void)in_sizes; (void)n_in; (void)out_size; (void)ws_size;
    const float* X       = (const float*)d_in[0];
    const float* log_pi  = (const float*)d_in[1];
    const float* mu      = (const float*)d_in[2];
    const float* Lambda  = (const float*)d_in[3];
    const float* log_psi = (const float*)d_in[4];
    float* out = (float*)d_out;
    float* ws  = (float*)d_ws;   // ~306 KB used

    precompute_kernel<<<dim3(KC), dim3(256), 0, stream>>>(log_pi, mu, Lambda, log_psi, ws);
    main_kernel<<<dim3(NPTS / NROW), dim3(512), 0, stream>>>(X, ws, out);
}

// Round 11
// 82.082 us; speedup vs baseline: 1.3137x; 1.0266x over previous
//
#include <hip/hip_runtime.h>
#include <math.h>

#define KC 32      // components
#define DD 256     // dims
#define QQ 16      // rank
#define NPTS 4096
#define NROW 16    // rows per main block
#define LOG2PI_F 1.8378770664093453f

typedef unsigned short ushort_t;

// ws layout (float offsets)
#define OFF_U    0      // [512] u2 = L^-1 (Lhat . mu)   (rotated)
#define OFF_LOGC 512    // [32]  log_pi - 0.5*(D*log2pi + logdetC + ck)
#define OFF_HB   544    // ushort [576][256] bf16 panel:
                        //   rows   0-511: Lhat2 = Psi^-1 Lam L^-T (comp k, rank q) at k*16+q
                        //   rows 512-543: V  = psi_inv (comp c at 512+c)
                        //   rows 544-575: W  = psi_inv*mu

__device__ __forceinline__ ushort_t f2bf(float f) {
    union { float f; unsigned int u; } c; c.f = f;
    unsigned int u = c.u;
    return (ushort_t)((u + 0x7FFFu + ((u >> 16) & 1u)) >> 16);   // RNE
}
__device__ __forceinline__ float bf2f(ushort_t h) {
    union { unsigned int u; float f; } c; c.u = ((unsigned int)h) << 16;
    return c.f;
}

using short8 = __attribute__((ext_vector_type(8))) short;   // 8 bf16 (4 VGPRs)
using f32x4  = __attribute__((ext_vector_type(4))) float;   // 4 fp32 acc

// ---------------- Kernel 1: per-component precompute (32 blocks x 256 thr) ----
// M,u via wave-0 MFMA; Cholesky M=LL^T; panel stores Lhat2 = Lhat L^-T, u2 = L^-1 u.
#define HSTR 264   // bf16 LDS row stride (ushorts)
__global__ __launch_bounds__(256) void precompute_kernel(
    const float* __restrict__ log_pi, const float* __restrict__ mu,
    const float* __restrict__ Lambda, const float* __restrict__ log_psi,
    float* __restrict__ ws)
{
    __shared__ __align__(16) ushort_t lamH[QQ * HSTR];   // bf16 Lam  [q][d]
    __shared__ __align__(16) ushort_t lhatH[QQ * HSTR];  // bf16 Lhat [q][d]
    __shared__ __align__(16) ushort_t smuH[QQ * HSTR];   // row0 = bf16 mu, rows1-15 zero
    __shared__ float sM[QQ * 17];
    __shared__ float sL[QQ * 17];
    __shared__ float sY[QQ * 17];    // L^-1
    __shared__ float sUvec[QQ];
    __shared__ float sPart[8];
    __shared__ float sScal[2];

    const int k = blockIdx.x;
    const int tid = threadIdx.x;
    const int lane = tid & 63;
    const int wave = tid >> 6;
    ushort_t* hb = (ushort_t*)(ws + OFF_HB);
    const int d = tid;   // exactly D threads

    float Psi  = expf(log_psi[k * DD + d]) + 1.1e-5f;  // exp+1e-6 then +1e-5 jitter
    float vinv = 1.0f / Psi;
    float mud  = mu[k * DD + d];
    float wv   = vinv * mud;
    hb[(512 + k) * DD + d] = f2bf(vinv);   // V row
    hb[(544 + k) * DD + d] = f2bf(wv);     // W row
    smuH[d] = f2bf(mud);                   // mu row 0
    float logPsi = logf(Psi);
    float ckp = wv * mud;

    // load Lambda row d (16 floats, kept fp32 in registers), bf16 Lam/Lhat to LDS
    float lam[QQ];
    {
        const float4* lrow = reinterpret_cast<const float4*>(Lambda + (size_t)(k * DD + d) * QQ);
#pragma unroll
        for (int i = 0; i < 4; ++i) {
            float4 t = lrow[i];
            lam[4 * i + 0] = t.x; lam[4 * i + 1] = t.y;
            lam[4 * i + 2] = t.z; lam[4 * i + 3] = t.w;
        }
#pragma unroll
        for (int q = 0; q < QQ; ++q) {
            lamH[q * HSTR + d]  = f2bf(lam[q]);
            lhatH[q * HSTR + d] = f2bf(lam[q] * vinv);
        }
    }
    // zero smuH rows 1-15 (990 ushort4)
#pragma unroll
    for (int i = 0; i < 4; ++i) {
        int idx = tid + i * 256;
        if (idx < 990)
            *reinterpret_cast<ushort4*>(smuH + HSTR + idx * 4) = make_ushort4(0, 0, 0, 0);
    }

    // block reduce sum(logPsi), sum(v*mu^2)
    float r0 = logPsi, r1 = ckp;
#pragma unroll
    for (int off = 32; off >= 1; off >>= 1) {
        r0 += __shfl_down(r0, off);
        r1 += __shfl_down(r1, off);
    }
    if ((tid & 63) == 0) { sPart[wave] = r0; sPart[4 + wave] = r1; }
    __syncthreads();                                            // B1 (fences staging too)
    if (tid == 0) {
        sScal[0] = sPart[0] + sPart[1] + sPart[2] + sPart[3];
        sScal[1] = sPart[4] + sPart[5] + sPart[6] + sPart[7];
    }

    // ---- wave 0 only: MFMA M,u -> Cholesky -> Y=L^-1 -> u2 ----
    if (wave == 0) {
        const int arow = lane & 15;
        const int quad = lane >> 4;
        const ushort_t* pa = lhatH + arow * HSTR + quad * 8;
        const ushort_t* pl = lamH  + arow * HSTR + quad * 8;
        const ushort_t* pm = smuH  + arow * HSTR + quad * 8;
        f32x4 accM = (f32x4){0.f, 0.f, 0.f, 0.f};
        f32x4 accU = (f32x4){0.f, 0.f, 0.f, 0.f};
#pragma unroll
        for (int ks = 0; ks < 8; ++ks) {
            short8 a = *reinterpret_cast<const short8*>(pa + ks * 32);
            accM = __builtin_amdgcn_mfma_f32_16x16x32_bf16(
                a, *reinterpret_cast<const short8*>(pl + ks * 32), accM, 0, 0, 0);
            accU = __builtin_amdgcn_mfma_f32_16x16x32_bf16(
                a, *reinterpret_cast<const short8*>(pm + ks * 32), accU, 0, 0, 0);
        }
        // C layout: col=lane&15 (-> r), row=quad*4+reg (-> q)
#pragma unroll
        for (int reg = 0; reg < 4; ++reg) {
            int q = quad * 4 + reg;
            sM[q * 17 + arow] = accM[reg] + ((q == arow) ? 1.0f : 0.0f);
        }
        if (arow == 0) {
#pragma unroll
            for (int reg = 0; reg < 4; ++reg)
                sUvec[quad * 4 + reg] = accU[reg];   // u[q]
        }

        // Cholesky (lanes 0..15), column broadcast via sL slot 16
        if (lane < QQ) {
            const int r = lane;
            float m[QQ], l[QQ];
#pragma unroll
            for (int c = 0; c < QQ; ++c) m[c] = sM[r * 17 + c];
#pragma unroll
            for (int j = 0; j < QQ; ++j) {
                float djj = __shfl(m[j], j);
                float rinv = 1.0f / sqrtf(djj);
                l[j] = m[j] * rinv;
                sL[r * 17 + 16] = l[j];          // publish column j
#pragma unroll
                for (int c = 0; c < QQ; ++c)
                    if (c > j) m[c] -= l[j] * sL[c * 17 + 16];
            }
#pragma unroll
            for (int j = 0; j < QQ; ++j) sL[r * 17 + j] = l[j];
            float dl = logf(l[r]);
            dl += __shfl_xor(dl, 1); dl += __shfl_xor(dl, 2);
            dl += __shfl_xor(dl, 4); dl += __shfl_xor(dl, 8);
            if (r == 0) sPart[1] = dl;   // logdetL

            // Y = L^-1, column per lane: sY[j*17+c] = Linv[j][c]
            float y[QQ];
#pragma unroll
            for (int j = 0; j < QQ; ++j) {
                float acc = (j == r) ? 1.0f : 0.0f;
#pragma unroll
                for (int i = 0; i < QQ; ++i)
                    if (i < j) acc -= sL[j * 17 + i] * y[i];
                y[j] = acc / sL[j * 17 + j];
            }
#pragma unroll
            for (int j = 0; j < QQ; ++j) sY[j * 17 + r] = y[j];

            // u2 = L^-1 u : u2[r] = sum_i Linv[r][i] * u[i]
            float u2 = 0.f;
#pragma unroll
            for (int i = 0; i < QQ; ++i)
                u2 += sY[r * 17 + i] * sUvec[i];
            ws[OFF_U + k * QQ + r] = u2;
        }
    }
    __syncthreads();                                            // B2

    // Lhat2 = Lhat . L^-T : row d, all 256 threads; panel write (bf16, once)
    {
#pragma unroll
        for (int q = 0; q < QQ; ++q) {
            float acc = 0.f;
#pragma unroll
            for (int j = 0; j < QQ; ++j)
                acc += lam[j] * sY[q * 17 + j];     // Linv[q][j]
            hb[(k * QQ + q) * DD + d] = f2bf(vinv * acc);
        }
    }
    if (tid == 0) {
        float logdet = sScal[0] + 2.0f * sPart[1];  // sum log Psi + logdet M
        ws[OFF_LOGC + k] = log_pi[k] - 0.5f * ((float)DD * LOG2PI_F + logdet)
                         - 0.5f * sScal[1];         // fold ck in
    }
}

// ---------------- Kernel 2: MFMA GEMM + in-register corr + logsumexp ---------
// grid 256 blocks x 512 threads, 16 rows x all 32 comps.
// corr = || Lhat2^T x - u2 ||^2 computed by square+butterfly right after MFMA.
#define SXH 264   // bf16 X row stride (ushorts)
#define QSTR 68   // qx/sx row stride (floats)
#define CSTR 36   // corr row stride (floats)
#define SRS 36

__global__ __launch_bounds__(512, 2) void main_kernel(
    const float* __restrict__ X, const float* __restrict__ ws,
    float* __restrict__ out)
{
    const int tid  = threadIdx.x;
    const int lane = tid & 63;
    const int wave = tid >> 6;         // 0..7
    const int n0   = blockIdx.x * NROW;
    const ushort_t* hB = (const ushort_t*)(ws + OFF_HB);

    __shared__ __align__(16) ushort_t xh[NROW * SXH];
    __shared__ __align__(16) float    sQS[NROW * QSTR];  // qx (0-31), sx (32-63)
    __shared__ __align__(16) float    sCorr[NROW * CSTR];
    __shared__ float sU[512];
    __shared__ float sLogc[KC];
    __shared__ float sR[NROW * SRS];
    __shared__ float sLse[NROW];

    // ---- staging: X rows as bf16 + u2 + logc ----
    {
        const float4* gx = reinterpret_cast<const float4*>(X + (size_t)n0 * DD);
#pragma unroll
        for (int i = 0; i < 2; ++i) {
            int f = tid + i * 512;
            int row = f >> 6, d4 = f & 63;
            float4 v = gx[f];
            *reinterpret_cast<ushort4*>(&xh[row * SXH + d4 * 4]) =
                make_ushort4(f2bf(v.x), f2bf(v.y), f2bf(v.z), f2bf(v.w));
        }
        sU[tid] = ws[OFF_U + tid];
        if (tid < KC) sLogc[tid] = ws[OFF_LOGC + tid];
    }
    __syncthreads();

    // ---- MFMA over 4 Lhat2 tiles (2 passes of 2, bounded VGPR) + special ----
    {
        const int arow = lane & 15;
        const int quad = lane >> 4;
        short8 a[8];
        const ushort_t* ab = xh + arow * SXH + quad * 8;
#pragma unroll
        for (int ks = 0; ks < 8; ++ks) a[ks] = *reinterpret_cast<const short8*>(ab + ks * 32);

#pragma unroll
        for (int pass = 0; pass < 2; ++pass) {
            short8 b[2][8];
#pragma unroll
            for (int i = 0; i < 2; ++i) {
                const int tile = wave * 4 + pass * 2 + i;
                const ushort_t* gB = hB + (size_t)(tile * 16 + arow) * DD + quad * 8;
#pragma unroll
                for (int ks = 0; ks < 8; ++ks)
                    b[i][ks] = *reinterpret_cast<const short8*>(gB + ks * 32);
            }
            f32x4 acc[2];
#pragma unroll
            for (int i = 0; i < 2; ++i) acc[i] = (f32x4){0.f, 0.f, 0.f, 0.f};
#pragma unroll
            for (int ks = 0; ks < 8; ++ks)
#pragma unroll
                for (int i = 0; i < 2; ++i)
                    acc[i] = __builtin_amdgcn_mfma_f32_16x16x32_bf16(a[ks], b[i][ks], acc[i], 0, 0, 0);
#pragma unroll
            for (int i = 0; i < 2; ++i) {
                const int tile = wave * 4 + pass * 2 + i;
                float uu = sU[tile * 16 + arow];     // u2[comp=tile][q=arow]
                float s0 = acc[i][0] - uu, s1 = acc[i][1] - uu,
                      s2 = acc[i][2] - uu, s3 = acc[i][3] - uu;
                s0 *= s0; s1 *= s1; s2 *= s2; s3 *= s3;
                // butterfly over the 16 arow-lanes (masks 1,2,4,8 stay in-quad)
#pragma unroll
                for (int mask = 1; mask < 16; mask <<= 1) {
                    s0 += __shfl_xor(s0, mask);
                    s1 += __shfl_xor(s1, mask);
                    s2 += __shfl_xor(s2, mask);
                    s3 += __shfl_xor(s3, mask);
                }
                if (arow == 0) {
                    sCorr[(quad * 4 + 0) * CSTR + tile] = s0;
                    sCorr[(quad * 4 + 1) * CSTR + tile] = s1;
                    sCorr[(quad * 4 + 2) * CSTR + tile] = s2;
                    sCorr[(quad * 4 + 3) * CSTR + tile] = s3;
                }
            }
        }
        if (wave < 4) {
            short8 aa[8];
            if (wave < 2) {   // A = X^2 (bf16) for qx tiles
#pragma unroll
                for (int ks = 0; ks < 8; ++ks) {
                    short8 sq;
#pragma unroll
                    for (int e = 0; e < 8; ++e) {
                        float xf = bf2f((ushort_t)a[ks][e]);
                        sq[e] = (short)f2bf(xf * xf);
                    }
                    aa[ks] = sq;
                }
            } else {
#pragma unroll
                for (int ks = 0; ks < 8; ++ks) aa[ks] = a[ks];
            }
            const ushort_t* gB = hB + (size_t)(512 + wave * 16 + arow) * DD + quad * 8;
            f32x4 accs = (f32x4){0.f, 0.f, 0.f, 0.f};
#pragma unroll
            for (int ks = 0; ks < 8; ++ks)
                accs = __builtin_amdgcn_mfma_f32_16x16x32_bf16(
                    aa[ks], *reinterpret_cast<const short8*>(gB + ks * 32), accs, 0, 0, 0);
            const int col = (wave & 1) * 16 + arow + ((wave >> 1) & 1) * 32;
#pragma unroll
            for (int r = 0; r < 4; ++r)
                sQS[(quad * 4 + r) * QSTR + col] = accs[r];
        }
    }
    __syncthreads();

    // ---- combine: one thread per (row, comp) ----
    {
        const int row = tid & 15, c = tid >> 4;
        float qx   = sQS[row * QSTR + c];
        float sx   = sQS[row * QSTR + 32 + c];
        float corr = sCorr[row * CSTR + c];
        sR[row * SRS + c] = sLogc[c] - 0.5f * (qx - 2.0f * sx - corr);
    }
    __syncthreads();

    // ---- logsumexp per row + outputs ----
    if (tid < NROW) {
        float m = -INFINITY;
#pragma unroll
        for (int c = 0; c < KC; ++c) m = fmaxf(m, sR[tid * SRS + c]);
        float sum = 0.f;
#pragma unroll
        for (int c = 0; c < KC; ++c) sum += expf(sR[tid * SRS + c] - m);
        float lse = m + logf(sum);
        sLse[tid] = lse;
        out[(size_t)NPTS * KC + n0 + tid] = lse;
    }
    __syncthreads();
    if (tid < NROW * 8) {
        int r = tid >> 3, i = tid & 7;
        float lse = sLse[r];
        float4 v = *reinterpret_cast<const float4*>(sR + r * SRS + i * 4);
        float4 o = make_float4(v.x - lse, v.y - lse, v.z - lse, v.w - lse);
        *reinterpret_cast<float4*>(out + (size_t)(n0 + r) * KC + i * 4) = o;
    }
}

extern "C" void kernel_launch(void* const* d_in, const int* in_sizes, int n_in,
                              void* d_out, int out_size, void* d_ws, size_t ws_size,
                              hipStream_t stream)
{
    (void)in_sizes; (void)n_in; (void)out_size; (void)ws_size;
    const float* X       = (const float*)d_in[0];
    const float* log_pi  = (const float*)d_in[1];
    const float* mu      = (const float*)d_in[2];
    const float* Lambda  = (const float*)d_in[3];
    const float* log_psi = (const float*)d_in[4];
    float* out = (float*)d_out;
    float* ws  = (float*)d_ws;   // ~290 KB used

    precompute_kernel<<<dim3(KC), dim3(256), 0, stream>>>(log_pi, mu, Lambda, log_psi, ws);
    main_kernel<<<dim3(NPTS / NROW), dim3(512), 0, stream>>>(X, ws, out);
}

// Round 12
// 80.293 us; speedup vs baseline: 1.3430x; 1.0223x over previous
//
#include <hip/hip_runtime.h>
#include <math.h>

#define KC 32      // components
#define DD 256     // dims
#define QQ 16      // rank
#define NPTS 4096
#define NROW 16    // rows per main block
#define LOG2PI_F 1.8378770664093453f

typedef unsigned short ushort_t;

// ws layout (float offsets)
#define OFF_U    0      // [512] u2 = L^-1 (Lhat . mu)   (rotated)
#define OFF_LOGC 512    // [32]  log_pi - 0.5*(D*log2pi + logdetC + ck)
#define OFF_HB   544    // ushort [576][256] bf16 panel:
                        //   rows   0-511: Lhat2 = Psi^-1 Lam L^-T (comp k, rank q) at k*16+q
                        //   rows 512-543: V  = psi_inv (comp c at 512+c)
                        //   rows 544-575: W  = psi_inv*mu

__device__ __forceinline__ ushort_t f2bf(float f) {
    union { float f; unsigned int u; } c; c.f = f;
    unsigned int u = c.u;
    return (ushort_t)((u + 0x7FFFu + ((u >> 16) & 1u)) >> 16);   // RNE
}
__device__ __forceinline__ float bf2f(ushort_t h) {
    union { unsigned int u; float f; } c; c.u = ((unsigned int)h) << 16;
    return c.f;
}

using short8 = __attribute__((ext_vector_type(8))) short;   // 8 bf16 (4 VGPRs)
using f32x4  = __attribute__((ext_vector_type(4))) float;   // 4 fp32 acc

// ---------------- Kernel 1: per-component precompute (32 blocks x 256 thr) ----
// M,u via wave-0 MFMA; Cholesky M=LL^T; panel stores Lhat2 = Lhat L^-T, u2 = L^-1 u.
#define HSTR 264   // bf16 LDS row stride (ushorts)
__global__ __launch_bounds__(256) void precompute_kernel(
    const float* __restrict__ log_pi, const float* __restrict__ mu,
    const float* __restrict__ Lambda, const float* __restrict__ log_psi,
    float* __restrict__ ws)
{
    __shared__ __align__(16) ushort_t lamH[QQ * HSTR];   // bf16 Lam  [q][d]
    __shared__ __align__(16) ushort_t lhatH[QQ * HSTR];  // bf16 Lhat [q][d]
    __shared__ __align__(16) ushort_t smuH[QQ * HSTR];   // row0 = bf16 mu, rows1-15 zero
    __shared__ float sM[QQ * 17];
    __shared__ float sL[QQ * 17];
    __shared__ float sY[QQ * 17];    // L^-1
    __shared__ float sUvec[QQ];
    __shared__ float sPart[8];
    __shared__ float sScal[2];

    const int k = blockIdx.x;
    const int tid = threadIdx.x;
    const int lane = tid & 63;
    const int wave = tid >> 6;
    ushort_t* hb = (ushort_t*)(ws + OFF_HB);
    const int d = tid;   // exactly D threads

    float Psi  = expf(log_psi[k * DD + d]) + 1.1e-5f;  // exp+1e-6 then +1e-5 jitter
    float vinv = 1.0f / Psi;
    float mud  = mu[k * DD + d];
    float wv   = vinv * mud;
    hb[(512 + k) * DD + d] = f2bf(vinv);   // V row
    hb[(544 + k) * DD + d] = f2bf(wv);     // W row
    smuH[d] = f2bf(mud);                   // mu row 0
    float logPsi = logf(Psi);
    float ckp = wv * mud;

    // load Lambda row d (16 floats, kept fp32 in registers), bf16 Lam/Lhat to LDS
    float lam[QQ];
    {
        const float4* lrow = reinterpret_cast<const float4*>(Lambda + (size_t)(k * DD + d) * QQ);
#pragma unroll
        for (int i = 0; i < 4; ++i) {
            float4 t = lrow[i];
            lam[4 * i + 0] = t.x; lam[4 * i + 1] = t.y;
            lam[4 * i + 2] = t.z; lam[4 * i + 3] = t.w;
        }
#pragma unroll
        for (int q = 0; q < QQ; ++q) {
            lamH[q * HSTR + d]  = f2bf(lam[q]);
            lhatH[q * HSTR + d] = f2bf(lam[q] * vinv);
        }
    }
    // zero smuH rows 1-15 (990 ushort4)
#pragma unroll
    for (int i = 0; i < 4; ++i) {
        int idx = tid + i * 256;
        if (idx < 990)
            *reinterpret_cast<ushort4*>(smuH + HSTR + idx * 4) = make_ushort4(0, 0, 0, 0);
    }

    // block reduce sum(logPsi), sum(v*mu^2)
    float r0 = logPsi, r1 = ckp;
#pragma unroll
    for (int off = 32; off >= 1; off >>= 1) {
        r0 += __shfl_down(r0, off);
        r1 += __shfl_down(r1, off);
    }
    if ((tid & 63) == 0) { sPart[wave] = r0; sPart[4 + wave] = r1; }
    __syncthreads();                                            // B1 (fences staging too)
    if (tid == 0) {
        sScal[0] = sPart[0] + sPart[1] + sPart[2] + sPart[3];
        sScal[1] = sPart[4] + sPart[5] + sPart[6] + sPart[7];
    }

    // ---- wave 0 only: MFMA M,u -> Cholesky -> Y=L^-1 -> u2 ----
    if (wave == 0) {
        const int arow = lane & 15;
        const int quad = lane >> 4;
        const ushort_t* pa = lhatH + arow * HSTR + quad * 8;
        const ushort_t* pl = lamH  + arow * HSTR + quad * 8;
        const ushort_t* pm = smuH  + arow * HSTR + quad * 8;
        f32x4 accM = (f32x4){0.f, 0.f, 0.f, 0.f};
        f32x4 accU = (f32x4){0.f, 0.f, 0.f, 0.f};
#pragma unroll
        for (int ks = 0; ks < 8; ++ks) {
            short8 a = *reinterpret_cast<const short8*>(pa + ks * 32);
            accM = __builtin_amdgcn_mfma_f32_16x16x32_bf16(
                a, *reinterpret_cast<const short8*>(pl + ks * 32), accM, 0, 0, 0);
            accU = __builtin_amdgcn_mfma_f32_16x16x32_bf16(
                a, *reinterpret_cast<const short8*>(pm + ks * 32), accU, 0, 0, 0);
        }
        // C layout: col=lane&15 (-> r), row=quad*4+reg (-> q)
#pragma unroll
        for (int reg = 0; reg < 4; ++reg) {
            int q = quad * 4 + reg;
            sM[q * 17 + arow] = accM[reg] + ((q == arow) ? 1.0f : 0.0f);
        }
        if (arow == 0) {
#pragma unroll
            for (int reg = 0; reg < 4; ++reg)
                sUvec[quad * 4 + reg] = accU[reg];   // u[q]
        }

        // Cholesky (lanes 0..15), column broadcast via sL slot 16
        if (lane < QQ) {
            const int r = lane;
            float m[QQ], l[QQ];
#pragma unroll
            for (int c = 0; c < QQ; ++c) m[c] = sM[r * 17 + c];
#pragma unroll
            for (int j = 0; j < QQ; ++j) {
                float djj = __shfl(m[j], j);
                float rinv = 1.0f / sqrtf(djj);
                l[j] = m[j] * rinv;
                sL[r * 17 + 16] = l[j];          // publish column j
#pragma unroll
                for (int c = 0; c < QQ; ++c)
                    if (c > j) m[c] -= l[j] * sL[c * 17 + 16];
            }
#pragma unroll
            for (int j = 0; j < QQ; ++j) sL[r * 17 + j] = l[j];
            float dl = logf(l[r]);
            dl += __shfl_xor(dl, 1); dl += __shfl_xor(dl, 2);
            dl += __shfl_xor(dl, 4); dl += __shfl_xor(dl, 8);
            if (r == 0) sPart[1] = dl;   // logdetL

            // Y = L^-1, column per lane: sY[j*17+c] = Linv[j][c]
            float y[QQ];
#pragma unroll
            for (int j = 0; j < QQ; ++j) {
                float acc = (j == r) ? 1.0f : 0.0f;
#pragma unroll
                for (int i = 0; i < QQ; ++i)
                    if (i < j) acc -= sL[j * 17 + i] * y[i];
                y[j] = acc / sL[j * 17 + j];
            }
#pragma unroll
            for (int j = 0; j < QQ; ++j) sY[j * 17 + r] = y[j];

            // u2 = L^-1 u : u2[r] = sum_i Linv[r][i] * u[i]
            float u2 = 0.f;
#pragma unroll
            for (int i = 0; i < QQ; ++i)
                u2 += sY[r * 17 + i] * sUvec[i];
            ws[OFF_U + k * QQ + r] = u2;
        }
    }
    __syncthreads();                                            // B2

    // Lhat2 = Lhat . L^-T : row d, all 256 threads; panel write (bf16, once)
    {
#pragma unroll
        for (int q = 0; q < QQ; ++q) {
            float acc = 0.f;
#pragma unroll
            for (int j = 0; j < QQ; ++j)
                acc += lam[j] * sY[q * 17 + j];     // Linv[q][j]
            hb[(k * QQ + q) * DD + d] = f2bf(vinv * acc);
        }
    }
    if (tid == 0) {
        float logdet = sScal[0] + 2.0f * sPart[1];  // sum log Psi + logdet M
        ws[OFF_LOGC + k] = log_pi[k] - 0.5f * ((float)DD * LOG2PI_F + logdet)
                         - 0.5f * sScal[1];         // fold ck in
    }
}

// ---------------- Kernel 2: MFMA GEMM + in-register corr + fused lse ---------
// grid 256 blocks x 512 threads, 16 rows x all 32 comps. Only 2 barriers:
// stage -> MFMA(writes sQS/sCorr) -> combine+logsumexp+store (half-wave butterfly).
#define SXH 264   // bf16 X row stride (ushorts)
#define QSTR 68   // qx/sx row stride (floats)
#define CSTR 36   // corr row stride (floats)

__global__ __launch_bounds__(512, 2) void main_kernel(
    const float* __restrict__ X, const float* __restrict__ ws,
    float* __restrict__ out)
{
    const int tid  = threadIdx.x;
    const int lane = tid & 63;
    const int wave = tid >> 6;         // 0..7
    const int n0   = blockIdx.x * NROW;
    const ushort_t* hB = (const ushort_t*)(ws + OFF_HB);

    __shared__ __align__(16) ushort_t xh[NROW * SXH];
    __shared__ __align__(16) float    sQS[NROW * QSTR];  // qx (0-31), sx (32-63)
    __shared__ __align__(16) float    sCorr[NROW * CSTR];
    __shared__ float sU[512];
    __shared__ float sLogc[KC];

    // ---- staging: X rows as bf16 + u2 + logc ----
    {
        const float4* gx = reinterpret_cast<const float4*>(X + (size_t)n0 * DD);
#pragma unroll
        for (int i = 0; i < 2; ++i) {
            int f = tid + i * 512;
            int row = f >> 6, d4 = f & 63;
            float4 v = gx[f];
            *reinterpret_cast<ushort4*>(&xh[row * SXH + d4 * 4]) =
                make_ushort4(f2bf(v.x), f2bf(v.y), f2bf(v.z), f2bf(v.w));
        }
        sU[tid] = ws[OFF_U + tid];
        if (tid < KC) sLogc[tid] = ws[OFF_LOGC + tid];
    }
    __syncthreads();                                            // B1

    // ---- MFMA over 4 Lhat2 tiles (2 passes of 2) + special qx/sx tiles ----
    {
        const int arow = lane & 15;
        const int quad = lane >> 4;
        short8 a[8];
        const ushort_t* ab = xh + arow * SXH + quad * 8;
#pragma unroll
        for (int ks = 0; ks < 8; ++ks) a[ks] = *reinterpret_cast<const short8*>(ab + ks * 32);

#pragma unroll
        for (int pass = 0; pass < 2; ++pass) {
            short8 b[2][8];
#pragma unroll
            for (int i = 0; i < 2; ++i) {
                const int tile = wave * 4 + pass * 2 + i;
                const ushort_t* gB = hB + (size_t)(tile * 16 + arow) * DD + quad * 8;
#pragma unroll
                for (int ks = 0; ks < 8; ++ks)
                    b[i][ks] = *reinterpret_cast<const short8*>(gB + ks * 32);
            }
            f32x4 acc[2];
#pragma unroll
            for (int i = 0; i < 2; ++i) acc[i] = (f32x4){0.f, 0.f, 0.f, 0.f};
#pragma unroll
            for (int ks = 0; ks < 8; ++ks)
#pragma unroll
                for (int i = 0; i < 2; ++i)
                    acc[i] = __builtin_amdgcn_mfma_f32_16x16x32_bf16(a[ks], b[i][ks], acc[i], 0, 0, 0);
#pragma unroll
            for (int i = 0; i < 2; ++i) {
                const int tile = wave * 4 + pass * 2 + i;
                float uu = sU[tile * 16 + arow];     // u2[comp=tile][q=arow]
                float s0 = acc[i][0] - uu, s1 = acc[i][1] - uu,
                      s2 = acc[i][2] - uu, s3 = acc[i][3] - uu;
                s0 *= s0; s1 *= s1; s2 *= s2; s3 *= s3;
                // butterfly over the 16 arow-lanes (masks 1,2,4,8 stay in-quad)
#pragma unroll
                for (int mask = 1; mask < 16; mask <<= 1) {
                    s0 += __shfl_xor(s0, mask);
                    s1 += __shfl_xor(s1, mask);
                    s2 += __shfl_xor(s2, mask);
                    s3 += __shfl_xor(s3, mask);
                }
                if (arow == 0) {
                    sCorr[(quad * 4 + 0) * CSTR + tile] = s0;
                    sCorr[(quad * 4 + 1) * CSTR + tile] = s1;
                    sCorr[(quad * 4 + 2) * CSTR + tile] = s2;
                    sCorr[(quad * 4 + 3) * CSTR + tile] = s3;
                }
            }
        }
        if (wave < 4) {
            short8 aa[8];
            if (wave < 2) {   // A = X^2 (bf16) for qx tiles
#pragma unroll
                for (int ks = 0; ks < 8; ++ks) {
                    short8 sq;
#pragma unroll
                    for (int e = 0; e < 8; ++e) {
                        float xf = bf2f((ushort_t)a[ks][e]);
                        sq[e] = (short)f2bf(xf * xf);
                    }
                    aa[ks] = sq;
                }
            } else {
#pragma unroll
                for (int ks = 0; ks < 8; ++ks) aa[ks] = a[ks];
            }
            const ushort_t* gB = hB + (size_t)(512 + wave * 16 + arow) * DD + quad * 8;
            f32x4 accs = (f32x4){0.f, 0.f, 0.f, 0.f};
#pragma unroll
            for (int ks = 0; ks < 8; ++ks)
                accs = __builtin_amdgcn_mfma_f32_16x16x32_bf16(
                    aa[ks], *reinterpret_cast<const short8*>(gB + ks * 32), accs, 0, 0, 0);
            const int col = (wave & 1) * 16 + arow + ((wave >> 1) & 1) * 32;
#pragma unroll
            for (int r = 0; r < 4; ++r)
                sQS[(quad * 4 + r) * QSTR + col] = accs[r];
        }
    }
    __syncthreads();                                            // B2

    // ---- combine + logsumexp + store: row's 32 comps = 32 consecutive lanes ----
    {
        const int row = tid >> 5;          // 0..15
        const int c   = tid & 31;          // comp
        float qx   = sQS[row * QSTR + c];
        float sx   = sQS[row * QSTR + 32 + c];
        float corr = sCorr[row * CSTR + c];
        float val  = sLogc[c] - 0.5f * (qx - 2.0f * sx - corr);

        // 32-lane aligned group: masks 1..16 stay inside the group
        float m = val;
#pragma unroll
        for (int mask = 1; mask < 32; mask <<= 1)
            m = fmaxf(m, __shfl_xor(m, mask));
        float e = expf(val - m);
        float s = e;
#pragma unroll
        for (int mask = 1; mask < 32; mask <<= 1)
            s += __shfl_xor(s, mask);
        float lse = m + logf(s);

        out[(size_t)(n0 + row) * KC + c] = val - lse;
        if (c == 0) out[(size_t)NPTS * KC + n0 + row] = lse;
    }
}

extern "C" void kernel_launch(void* const* d_in, const int* in_sizes, int n_in,
                              void* d_out, int out_size, void* d_ws, size_t ws_size,
                              hipStream_t stream)
{
    (void)in_sizes; (void)n_in; (void)out_size; (void)ws_size;
    const float* X       = (const float*)d_in[0];
    const float* log_pi  = (const float*)d_in[1];
    const float* mu      = (const float*)d_in[2];
    const float* Lambda  = (const float*)d_in[3];
    const float* log_psi = (const float*)d_in[4];
    float* out = (float*)d_out;
    float* ws  = (float*)d_ws;   // ~290 KB used

    precompute_kernel<<<dim3(KC), dim3(256), 0, stream>>>(log_pi, mu, Lambda, log_psi, ws);
    main_kernel<<<dim3(NPTS / NROW), dim3(512), 0, stream>>>(X, ws, out);
}